// Round 3
// baseline (537.853 us; speedup 1.0000x reference)
//
#include <hip/hip_runtime.h>
#include <hip/hip_bf16.h>

typedef __bf16 bf16;
typedef __bf16 bf16x8 __attribute__((ext_vector_type(8)));
typedef __bf16 bf16x4 __attribute__((ext_vector_type(4)));
typedef float  f32x4  __attribute__((ext_vector_type(4)));

#define NB 8
#define NS 1024
#define ND 1024
#define NH 16
#define NDK 64
#define NDFF 4096

static __device__ __forceinline__ f32x4 mfma16(bf16x8 a, bf16x8 b, f32x4 c) {
    return __builtin_amdgcn_mfma_f32_16x16x32_bf16(a, b, c, 0, 0, 0);
}

#define GLDS(g, l) __builtin_amdgcn_global_load_lds( \
    (const __attribute__((address_space(1))) void*)(g), \
    (__attribute__((address_space(3))) void*)(l), 16, 0, 0)

// fp32 -> bf16 elementwise (n4 = count/4)
__global__ __launch_bounds__(256) void cvt_x(const float* __restrict__ in,
                                             bf16* __restrict__ out, int n4)
{
    int idx = blockIdx.x * 256 + threadIdx.x;
    if (idx >= n4) return;
    float4 v = ((const float4*)in)[idx];
    bf16x4 o = { (bf16)v.x, (bf16)v.y, (bf16)v.z, (bf16)v.w };
    ((bf16x4*)out)[idx] = o;
}

// ---------------------------------------------------------------------------
// Weight prep: fp32 src -> bf16 BT layout [N][K]; fold 0.125 into Wq (exact).
// ---------------------------------------------------------------------------
__global__ __launch_bounds__(256) void prep_transpose(
    const float* __restrict__ Wq, const float* __restrict__ Wk, const float* __restrict__ Wv,
    const float* __restrict__ Wo, const float* __restrict__ W1, const float* __restrict__ W2,
    bf16* __restrict__ wqkvT, bf16* __restrict__ WoT,
    bf16* __restrict__ W1T, bf16* __restrict__ W2T)
{
    __shared__ float T[64][65];
    int bid = blockIdx.x;
    const float* src; bf16* dst; int srcLd, dstLd, tR, tC; bool scale = false;
    if (bid < 768) {                       // Wq/Wk/Wv: per-head [1024x64] -> [64x1024]
        int mat = bid >> 4, ty = bid & 15;
        int h = mat & 15, type = mat >> 4;
        const float* W = (type == 0) ? Wq : (type == 1 ? Wk : Wv);
        src = W + (size_t)h * ND * NDK;
        srcLd = NDK; tR = ty * 64; tC = 0;
        dst = wqkvT + ((size_t)type * 1024 + h * 64) * ND;
        dstLd = ND;
        scale = (type == 0);
    } else if (bid < 1024) {               // Wo [1024x1024] -> WoT
        int b2 = bid - 768; int ty = b2 >> 4, tx = b2 & 15;
        src = Wo; srcLd = ND; tR = ty * 64; tC = tx * 64; dst = WoT; dstLd = ND;
    } else if (bid < 2048) {               // W1 [1024x4096] -> W1T [4096x1024]
        int b2 = bid - 1024; int ty = b2 >> 6, tx = b2 & 63;
        src = W1; srcLd = NDFF; tR = ty * 64; tC = tx * 64; dst = W1T; dstLd = ND;
    } else {                               // W2 [4096x1024] -> W2T [1024x4096]
        int b2 = bid - 2048; int ty = b2 >> 4, tx = b2 & 15;
        src = W2; srcLd = ND; tR = ty * 64; tC = tx * 64; dst = W2T; dstLd = NDFF;
    }
    int t = threadIdx.x;
    int c0 = t & 63, r0 = t >> 6;
    #pragma unroll
    for (int rr = 0; rr < 16; rr++) {
        int row = rr * 4 + r0;
        T[row][c0] = src[(size_t)(tR + row) * srcLd + tC + c0];
    }
    __syncthreads();
    #pragma unroll
    for (int cc = 0; cc < 16; cc++) {
        int col = cc * 4 + r0;
        float v = T[c0][col];
        if (scale) v *= 0.125f;
        dst[(size_t)(tC + col) * dstLd + tR + c0] = (bf16)v;
    }
}

__global__ void prep_bias(const float* __restrict__ bq, const float* __restrict__ bk,
                          const float* __restrict__ bv, float* __restrict__ bqkv)
{
    int n = blockIdx.x * 256 + threadIdx.x;
    if (n >= 3072) return;
    int type = n >> 10, hk = n & 1023;
    const float* bb = (type == 0) ? bq : (type == 1 ? bk : bv);
    float v = bb[hk];
    if (type == 0) v *= 0.125f;
    bqkv[n] = v;
}

// ---------------------------------------------------------------------------
// Deep-prefetch GEMM core v3: C = A[M,K] * BT[N,K]^T, BM=256, BK=64, 8 waves
// (2M x 4N), per-wave output 128 x BN/4. NO intra-tile barriers, NO manual
// lgkm waits: per K-tile the whole quadrant sequence is straight-line code and
// the compiler interleaves ds_reads under MFMAs with its own counted lgkmcnt
// (m97 evidence: that interleave is near-optimal). Next tile's gloads are all
// issued at tile START into the idle dbuf half; the single vmcnt(0)+barrier at
// the tile boundary then waits on loads issued ~2500 cy earlier (>> HBM
// latency) and is amortized over 64 MFMA. Cluster order m0h0,m0h1,m1h1,m1h0
// keeps b0 live (no frag re-reads); peak live frags = 16 (a+b) -> ~<256 VGPR.
// XOR-8 LDS swizzle via pre-swizzled global source (0 conflicts, verified).
// ---------------------------------------------------------------------------
template<int BN>
__device__ __forceinline__ void gemm_dp(
    const bf16* __restrict__ A, const bf16* __restrict__ BT, int K,
    int rowBase, int colBase, f32x4 (&acc)[8][BN / 64], bf16* As, bf16* Bs)
{
    constexpr int NF = BN / 64;       // acc columns per wave (2 or 4)
    constexpr int NHF = NF / 2;       // B frags per n-half (1 or 2)
    constexpr int ABUF = 256 * 64, BBUF = BN * 64;
    constexpr int BR = BN / 64;       // B gloads per K-tile
    const int tid = threadIdx.x, lane = tid & 63, wid = tid >> 6;
    const int wm = wid >> 2, wn = wid & 3;
    const int lrow = lane & 15, lq = lane >> 4;
    const int srow = lane >> 3, gblk = (lane & 7) ^ srow;
    const int co0 = (lq ^ (lrow & 7)) * 8;
    const int co1 = ((4 + lq) ^ (lrow & 7)) * 8;
    f32x4 zz = {0.f, 0.f, 0.f, 0.f};
    #pragma unroll
    for (int i = 0; i < 8; i++)
        #pragma unroll
        for (int j = 0; j < NF; j++) acc[i][j] = zz;
    const bf16* Ag = A  + (size_t)(rowBase + wid * 8 + srow) * K + gblk * 8;
    const bf16* Bg = BT + (size_t)(colBase + wid * 8 + srow) * K + gblk * 8;

#define STAGE_DP(kt, bi) do { \
    _Pragma("unroll") \
    for (int r_ = 0; r_ < 4; r_++) \
        GLDS(Ag + (size_t)(kt) * 64 + (size_t)r_ * 64 * K, \
             As + (bi) * ABUF + (r_ * 64 + wid * 8) * 64); \
    _Pragma("unroll") \
    for (int r_ = 0; r_ < BR; r_++) \
        GLDS(Bg + (size_t)(kt) * 64 + (size_t)r_ * 64 * K, \
             Bs + (bi) * BBUF + (r_ * 64 + wid * 8) * 64); \
} while (0)

#define RDA_DP(dst, ms) do { _Pragma("unroll") for (int i_ = 0; i_ < 4; i_++) { \
    int ro_ = (wm * 128 + (ms) * 64 + i_ * 16 + lrow) * 64; \
    dst[i_][0] = *(const bf16x8*)&Ab[ro_ + co0]; \
    dst[i_][1] = *(const bf16x8*)&Ab[ro_ + co1]; } } while (0)

#define RDB_DP(dst, h) do { _Pragma("unroll") for (int j_ = 0; j_ < NHF; j_++) { \
    int ro_ = (wn * (BN / 4) + (h) * (BN / 8) + j_ * 16 + lrow) * 64; \
    dst[j_][0] = *(const bf16x8*)&Bb[ro_ + co0]; \
    dst[j_][1] = *(const bf16x8*)&Bb[ro_ + co1]; } } while (0)

#define CL_DP(av, bv, ms, h) do { \
    __builtin_amdgcn_s_setprio(1); \
    _Pragma("unroll") \
    for (int i_ = 0; i_ < 4; i_++) \
        _Pragma("unroll") \
        for (int j_ = 0; j_ < NHF; j_++) { \
            acc[(ms) * 4 + i_][(h) * NHF + j_] = \
                mfma16(av[i_][0], bv[j_][0], acc[(ms) * 4 + i_][(h) * NHF + j_]); \
            acc[(ms) * 4 + i_][(h) * NHF + j_] = \
                mfma16(av[i_][1], bv[j_][1], acc[(ms) * 4 + i_][(h) * NHF + j_]); \
        } \
    __builtin_amdgcn_s_setprio(0); \
} while (0)

    const int nt = K >> 6;
    STAGE_DP(0, 0);
    asm volatile("s_waitcnt vmcnt(0)" ::: "memory");
    __builtin_amdgcn_s_barrier();

    for (int t = 0; t < nt; ++t) {
        const int cur = t & 1;
        const bf16* Ab = As + cur * ABUF;
        const bf16* Bb = Bs + cur * BBUF;
        if (t + 1 < nt) STAGE_DP(t + 1, cur ^ 1);   // full next tile, max cover
        bf16x8 a0[4][2], a1[4][2], b0[NHF][2], b1[NHF][2];
        RDA_DP(a0, 0); RDB_DP(b0, 0);
        CL_DP(a0, b0, 0, 0);
        RDB_DP(b1, 1);
        CL_DP(a0, b1, 0, 1);
        RDA_DP(a1, 1);
        CL_DP(a1, b1, 1, 1);
        CL_DP(a1, b0, 1, 0);                        // b0 kept live, no re-read
        if (t + 1 < nt) {
            asm volatile("s_waitcnt vmcnt(0)" ::: "memory");  // loads issued ~1 tile ago
            __builtin_amdgcn_s_barrier();
        }
    }
#undef STAGE_DP
#undef RDA_DP
#undef RDB_DP
#undef CL_DP
}

// G1: xb @ [Wq|Wk|Wv] + bias; Q,K,V all row-major per (b,h).  BN=128, grid 768.
__global__ __launch_bounds__(512, 2) void g1_qkv(
    const bf16* __restrict__ x, const bf16* __restrict__ wqkvT, const float* __restrict__ bqkv,
    bf16* __restrict__ Q, bf16* __restrict__ Kb, bf16* __restrict__ Vb)
{
    __shared__ bf16 As[2 * 256 * 64], Bs[2 * 128 * 64];   // 96 KiB
    f32x4 acc[8][2];
    int g = blockIdx.x;
    int sw = (g & 7) * 96 + (g >> 3);                     // 768 % 8 == 0, bijective
    int bm = sw / 24, bn = sw % 24;                       // 32 x 24 tiles
    int rowBase = bm * 256, colBase = bn * 128;
    gemm_dp<128>(x, wqkvT, ND, rowBase, colBase, acc, As, Bs);
    const int tid = threadIdx.x, lane = tid & 63, wid = tid >> 6;
    const int wm = wid >> 2, wn = wid & 3, lrow = lane & 15, lq = lane >> 4;
    #pragma unroll
    for (int j = 0; j < 2; j++) {
        int gcol = colBase + wn * 32 + j * 16 + lrow;
        float bias = bqkv[gcol];
        int type = gcol >> 10, h = (gcol >> 6) & 15, kk = gcol & 63;
        bf16* dst = (type == 0) ? Q : (type == 1 ? Kb : Vb);
        #pragma unroll
        for (int i = 0; i < 8; i++) {
            #pragma unroll
            for (int r = 0; r < 4; r++) {
                int grow = rowBase + wm * 128 + i * 16 + lq * 4 + r;
                int b = grow >> 10, s = grow & 1023;
                dst[((size_t)(b * NH + h) * NS + s) * NDK + kk] = (bf16)(acc[i][j][r] + bias);
            }
        }
    }
}

// Vb [bh][s][kk] -> Vt [bh][kk][s]  (LDS-tiled transpose)
__global__ __launch_bounds__(256) void vt_trans(
    const bf16* __restrict__ Vb, bf16* __restrict__ Vt)
{
    __shared__ bf16 T[64 * 72];
    int bh = blockIdx.y, s0 = blockIdx.x * 64;
    const bf16* src = Vb + ((size_t)bh * NS + s0) * NDK;
    int tid = threadIdx.x;
    #pragma unroll
    for (int it = 0; it < 2; it++) {
        int g = tid + it * 256;
        int row = g >> 3, c = (g & 7) * 8;
        *(bf16x8*)&T[row * 72 + c] = *(const bf16x8*)&src[row * NDK + c];
    }
    __syncthreads();
    #pragma unroll
    for (int it = 0; it < 2; it++) {
        int g = tid + it * 256;
        int kk = g >> 3, sc = (g & 7) * 8;
        bf16x8 v;
        #pragma unroll
        for (int t = 0; t < 8; t++) v[t] = T[(sc + t) * 72 + kk];
        *(bf16x8*)&Vt[((size_t)bh * NDK + kk) * NS + s0 + sc] = v;
    }
}

// G2: per-key-column coefficients: unmasked (1/sum_i exp(s_ij), 0); masked (0, 1/1024).
__global__ __launch_bounds__(256) void g2_stats(
    const bf16* __restrict__ Q, const bf16* __restrict__ Kb,
    const int* __restrict__ mask, float2* __restrict__ alpha)
{
    __shared__ bf16 Qs[128 * 64];
    int bh = blockIdx.y, b = bh >> 4;
    int jBase = blockIdx.x * 128;
    const bf16* Kp = Kb + (size_t)bh * NS * NDK;
    const bf16* Qp = Q + (size_t)bh * NS * NDK;
    const int tid = threadIdx.x, lane = tid & 63, wid = tid >> 6;
    const int lrow = lane & 15, lq = lane >> 4;
    bf16x8 kf[2][2];
    #pragma unroll
    for (int jt = 0; jt < 2; jt++)
        #pragma unroll
        for (int kh = 0; kh < 2; kh++)
            kf[jt][kh] = *(const bf16x8*)&Kp[(size_t)(jBase + wid * 32 + jt * 16 + lrow) * NDK + kh * 32 + lq * 8];
    const int srow = lane >> 3;
    const int gblk = (lane & 7) ^ srow;
    float Lacc[2][4];
    #pragma unroll
    for (int jt = 0; jt < 2; jt++)
        #pragma unroll
        for (int r = 0; r < 4; r++) Lacc[jt][r] = 0.f;
    f32x4 zz = {0.f, 0.f, 0.f, 0.f};
    for (int i0 = 0; i0 < NS; i0 += 128) {
        __syncthreads();
        #pragma unroll
        for (int it = 0; it < 4; it++)
            GLDS(Qp + (size_t)(i0 + wid * 32 + it * 8 + srow) * NDK + gblk * 8,
                 Qs + (wid * 32 + it * 8) * 64);
        __syncthreads();
        #pragma unroll
        for (int it = 0; it < 8; it++) {
            bf16x8 qb[2];
            #pragma unroll
            for (int kh = 0; kh < 2; kh++)
                qb[kh] = *(const bf16x8*)&Qs[(it * 16 + lrow) * 64 + ((kh * 4 + lq) ^ (lrow & 7)) * 8];
            #pragma unroll
            for (int jt = 0; jt < 2; jt++) {
                f32x4 s = mfma16(kf[jt][0], qb[0], zz);
                s = mfma16(kf[jt][1], qb[1], s);
                #pragma unroll
                for (int r = 0; r < 4; r++) Lacc[jt][r] += __expf(s[r]);
            }
        }
    }
    #pragma unroll
    for (int jt = 0; jt < 2; jt++) {
        #pragma unroll
        for (int r = 0; r < 4; r++) {
            float v = Lacc[jt][r];
            v += __shfl_xor(v, 1); v += __shfl_xor(v, 2);
            v += __shfl_xor(v, 4); v += __shfl_xor(v, 8);
            if (lrow == 0) {
                int j = jBase + wid * 32 + jt * 16 + lq * 4 + r;
                int m = mask[b * NS + j];
                float2 ac;
                ac.x = m ? 1.f / v : 0.f;
                ac.y = m ? 0.f : (1.f / 1024.f);
                alpha[(size_t)bh * NS + j] = ac;
            }
        }
    }
}

// G3: ctx[i][kk] = sum_j (a_j*exp(s_ij)+c_j) * v[j][kk]
__global__ __launch_bounds__(256) void g3_ctx(
    const bf16* __restrict__ Q, const bf16* __restrict__ Kb, const bf16* __restrict__ Vt,
    const float2* __restrict__ alpha, bf16* __restrict__ ctx)
{
    __shared__ bf16 Ks[64 * 64];       // 8 KB
    __shared__ bf16 Vs[64 * 64];       // 8 KB
    __shared__ bf16 Ps[4 * 64 * 64];   // 32 KB, per-wave 8KB, XOR-swizzled
    int bh = blockIdx.y, iBase = blockIdx.x * 256;
    int b = bh >> 4, h = bh & 15;
    const bf16* Qp = Q + (size_t)bh * NS * NDK;
    const bf16* Kp = Kb + (size_t)bh * NS * NDK;
    const bf16* Vp = Vt + (size_t)bh * NDK * NS;
    const float2* al = alpha + (size_t)bh * NS;
    const int tid = threadIdx.x, lane = tid & 63, wid = tid >> 6;
    const int lrow = lane & 15, lq = lane >> 4;
    const int iw = iBase + wid * 64;
    bf16x8 qf[4][2];
    #pragma unroll
    for (int it = 0; it < 4; it++)
        #pragma unroll
        for (int kh = 0; kh < 2; kh++)
            qf[it][kh] = *(const bf16x8*)&Qp[(size_t)(iw + it * 16 + lrow) * NDK + kh * 32 + lq * 8];
    const int srow = lane >> 3;
    const int gblk = (lane & 7) ^ srow;
    f32x4 cacc[4][4];
    f32x4 zz = {0.f, 0.f, 0.f, 0.f};
    #pragma unroll
    for (int it = 0; it < 4; it++)
        #pragma unroll
        for (int kt = 0; kt < 4; kt++) cacc[it][kt] = zz;
    bf16* Pw = Ps + wid * 64 * 64;
    for (int j0 = 0; j0 < NS; j0 += 64) {
        __syncthreads();
        #pragma unroll
        for (int it = 0; it < 2; it++)
            GLDS(Kp + (size_t)(j0 + wid * 16 + it * 8 + srow) * NDK + gblk * 8,
                 Ks + (wid * 16 + it * 8) * 64);
        #pragma unroll
        for (int it = 0; it < 2; it++)
            GLDS(Vp + (size_t)(wid * 16 + it * 8 + srow) * NS + j0 + gblk * 8,
                 Vs + (wid * 16 + it * 8) * 64);
        __syncthreads();
        bf16x8 kb[4][2];
        #pragma unroll
        for (int jt = 0; jt < 4; jt++)
            #pragma unroll
            for (int kh = 0; kh < 2; kh++)
                kb[jt][kh] = *(const bf16x8*)&Ks[(jt * 16 + lrow) * 64 + ((kh * 4 + lq) ^ (lrow & 7)) * 8];
        #pragma unroll
        for (int jt = 0; jt < 4; jt++) {
            float2 acj[4];
            #pragma unroll
            for (int r = 0; r < 4; r++) acj[r] = al[j0 + jt * 16 + lq * 4 + r];
            #pragma unroll
            for (int it = 0; it < 4; it++) {
                f32x4 s = mfma16(kb[jt][0], qf[it][0], zz);
                s = mfma16(kb[jt][1], qf[it][1], s);
                bf16x4 pv;
                #pragma unroll
                for (int r = 0; r < 4; r++)
                    pv[r] = (bf16)(acj[r].x * __expf(s[r]) + acj[r].y);
                int i = it * 16 + lrow;
                int jb = jt * 2 + (lq >> 1);
                *(bf16x4*)&Pw[i * 64 + ((jb ^ (i & 7)) * 8) + (lq & 1) * 4] = pv;
            }
        }
        bf16x8 vb[4][2];
        #pragma unroll
        for (int kt = 0; kt < 4; kt++)
            #pragma unroll
            for (int kh = 0; kh < 2; kh++)
                vb[kt][kh] = *(const bf16x8*)&Vs[(kt * 16 + lrow) * 64 + ((kh * 4 + lq) ^ (lrow & 7)) * 8];
        #pragma unroll
        for (int it = 0; it < 4; it++) {
            bf16x8 pa[2];
            #pragma unroll
            for (int kh = 0; kh < 2; kh++)
                pa[kh] = *(const bf16x8*)&Pw[(it * 16 + lrow) * 64 + ((kh * 4 + lq) ^ (lrow & 7)) * 8];
            #pragma unroll
            for (int kt = 0; kt < 4; kt++) {
                cacc[it][kt] = mfma16(pa[0], vb[kt][0], cacc[it][kt]);
                cacc[it][kt] = mfma16(pa[1], vb[kt][1], cacc[it][kt]);
            }
        }
    }
    #pragma unroll
    for (int kt = 0; kt < 4; kt++) {
        int col = h * NDK + kt * 16 + lrow;
        #pragma unroll
        for (int it = 0; it < 4; it++) {
            #pragma unroll
            for (int r = 0; r < 4; r++) {
                int i = iw + it * 16 + lq * 4 + r;
                ctx[(size_t)(b * NS + i) * ND + col] = (bf16)cacc[it][kt][r];
            }
        }
    }
}

// G4: t1b = bf16(ctx @ Wo + bo + xb)   BN=128, grid 256
__global__ __launch_bounds__(512, 2) void g4_proj(
    const bf16* __restrict__ ctx, const bf16* __restrict__ WoT, const float* __restrict__ bo,
    const bf16* __restrict__ xb, bf16* __restrict__ t1b)
{
    __shared__ bf16 As[2 * 256 * 64], Bs[2 * 128 * 64];   // 96 KiB
    f32x4 acc[8][2];
    int g = blockIdx.x;
    int sw = (g & 7) * 32 + (g >> 3);
    int bm = sw >> 3, bn = sw & 7;                        // 32 x 8 tiles
    int rowBase = bm * 256, colBase = bn * 128;
    gemm_dp<128>(ctx, WoT, ND, rowBase, colBase, acc, As, Bs);
    const int tid = threadIdx.x, lane = tid & 63, wid = tid >> 6;
    const int wm = wid >> 2, wn = wid & 3, lrow = lane & 15, lq = lane >> 4;
    #pragma unroll
    for (int j = 0; j < 2; j++) {
        int gcol = colBase + wn * 32 + j * 16 + lrow;
        float bias = bo[gcol];
        #pragma unroll
        for (int i = 0; i < 8; i++) {
            #pragma unroll
            for (int r = 0; r < 4; r++) {
                int grow = rowBase + wm * 128 + i * 16 + lq * 4 + r;
                float v = acc[i][j][r] + bias + (float)xb[(size_t)grow * ND + gcol];
                t1b[(size_t)grow * ND + gcol] = (bf16)v;
            }
        }
    }
}

// G5: hb = relu(yb @ W1 + b1)   BN=256, grid 512
__global__ __launch_bounds__(512, 2) void g5_ffn1(
    const bf16* __restrict__ y, const bf16* __restrict__ W1T, const float* __restrict__ b1,
    bf16* __restrict__ hb)
{
    __shared__ bf16 As[2 * 256 * 64], Bs[2 * 256 * 64];   // 128 KiB
    f32x4 acc[8][4];
    int g = blockIdx.x;
    int sw = (g & 7) * 64 + (g >> 3);
    int bm = sw >> 4, bn = sw & 15;                       // 32 x 16 tiles
    int rowBase = bm * 256, colBase = bn * 256;
    gemm_dp<256>(y, W1T, ND, rowBase, colBase, acc, As, Bs);
    const int tid = threadIdx.x, lane = tid & 63, wid = tid >> 6;
    const int wm = wid >> 2, wn = wid & 3, lrow = lane & 15, lq = lane >> 4;
    #pragma unroll
    for (int j = 0; j < 4; j++) {
        int gcol = colBase + wn * 64 + j * 16 + lrow;
        float bias = b1[gcol];
        #pragma unroll
        for (int i = 0; i < 8; i++) {
            #pragma unroll
            for (int r = 0; r < 4; r++) {
                int grow = rowBase + wm * 128 + i * 16 + lq * 4 + r;
                float v = fmaxf(acc[i][j][r] + bias, 0.f);
                hb[(size_t)grow * NDFF + gcol] = (bf16)v;
            }
        }
    }
}

// G6: zb = bf16(hb @ W2 + b2 + yb)   BN=128, grid 256, K=4096
__global__ __launch_bounds__(512, 2) void g6_ffn2(
    const bf16* __restrict__ hb, const bf16* __restrict__ W2T, const float* __restrict__ b2,
    const bf16* __restrict__ yb, bf16* __restrict__ zb)
{
    __shared__ bf16 As[2 * 256 * 64], Bs[2 * 128 * 64];   // 96 KiB
    f32x4 acc[8][2];
    int g = blockIdx.x;
    int sw = (g & 7) * 32 + (g >> 3);
    int bm = sw >> 3, bn = sw & 7;                        // 32 x 8 tiles
    int rowBase = bm * 256, colBase = bn * 128;
    gemm_dp<128>(hb, W2T, NDFF, rowBase, colBase, acc, As, Bs);
    const int tid = threadIdx.x, lane = tid & 63, wid = tid >> 6;
    const int wm = wid >> 2, wn = wid & 3, lrow = lane & 15, lq = lane >> 4;
    #pragma unroll
    for (int j = 0; j < 2; j++) {
        int gcol = colBase + wn * 32 + j * 16 + lrow;
        float bias = b2[gcol];
        #pragma unroll
        for (int i = 0; i < 8; i++) {
            #pragma unroll
            for (int r = 0; r < 4; r++) {
                int grow = rowBase + wm * 128 + i * 16 + lq * 4 + r;
                float v = acc[i][j][r] + bias + (float)yb[(size_t)grow * ND + gcol];
                zb[(size_t)grow * ND + gcol] = (bf16)v;
            }
        }
    }
}

// Row LayerNorm over D=1024, bf16 in; writes bf16 (outb) and/or fp32 (outf)
__global__ __launch_bounds__(256) void ln_kernel(
    const bf16* __restrict__ in, bf16* __restrict__ outb, float* __restrict__ outf,
    const float* __restrict__ g, const float* __restrict__ bb)
{
    int row = blockIdx.x, tid = threadIdx.x;
    const bf16* p = in + (size_t)row * ND;
    bf16x4 v4 = *(const bf16x4*)&p[tid * 4];
    float vv[4] = {(float)v4[0], (float)v4[1], (float)v4[2], (float)v4[3]};
    float s = vv[0] + vv[1] + vv[2] + vv[3];
    float q = vv[0]*vv[0] + vv[1]*vv[1] + vv[2]*vv[2] + vv[3]*vv[3];
    #pragma unroll
    for (int m = 1; m < 64; m <<= 1) { s += __shfl_xor(s, m); q += __shfl_xor(q, m); }
    __shared__ float rs[4], rq[4];
    int wid = tid >> 6, lane = tid & 63;
    if (lane == 0) { rs[wid] = s; rq[wid] = q; }
    __syncthreads();
    s = rs[0] + rs[1] + rs[2] + rs[3];
    q = rq[0] + rq[1] + rq[2] + rq[3];
    float mean = s * (1.f / 1024.f);
    float var = q * (1.f / 1024.f) - mean * mean;
    float rstd = 1.f / sqrtf(var + 1e-5f);
    float4 of;
    bf16x4 ob;
    #pragma unroll
    for (int k = 0; k < 4; k++) {
        int col = tid * 4 + k;
        float yv = (vv[k] - mean) * rstd * g[col] + bb[col];
        ((float*)&of)[k] = yv;
        ob[k] = (bf16)yv;
    }
    if (outb) *(bf16x4*)&outb[(size_t)row * ND + tid * 4] = ob;
    if (outf) ((float4*)(outf + (size_t)row * ND))[tid] = of;
}

// ---------------------------------------------------------------------------
extern "C" void kernel_launch(void* const* d_in, const int* in_sizes, int n_in,
                              void* d_out, int out_size, void* d_ws, size_t ws_size,
                              hipStream_t stream)
{
    const float* x    = (const float*)d_in[0];
    const int*   mask = (const int*)d_in[1];
    const float* Wq   = (const float*)d_in[2];
    const float* bq   = (const float*)d_in[3];
    const float* Wk   = (const float*)d_in[4];
    const float* bk   = (const float*)d_in[5];
    const float* Wv   = (const float*)d_in[6];
    const float* bv   = (const float*)d_in[7];
    const float* Wo   = (const float*)d_in[8];
    const float* bo   = (const float*)d_in[9];
    const float* ga   = (const float*)d_in[10];
    const float* ba   = (const float*)d_in[11];
    const float* W1   = (const float*)d_in[12];
    const float* b1   = (const float*)d_in[13];
    const float* W2   = (const float*)d_in[14];
    const float* b2   = (const float*)d_in[15];
    const float* gf   = (const float*)d_in[16];
    const float* bfb  = (const float*)d_in[17];

    size_t off = 0;
    auto alloc = [&](size_t n) { char* p = (char*)d_ws + off; off += (n + 255) & ~(size_t)255; return (void*)p; };
    bf16*   wqkvT = (bf16*)  alloc((size_t)3072 * 1024 * 2);           // 6 MB
    bf16*   WoT   = (bf16*)  alloc((size_t)1024 * 1024 * 2);           // 2 MB
    bf16*   W1T   = (bf16*)  alloc((size_t)4096 * 1024 * 2);           // 8 MB
    bf16*   W2T   = (bf16*)  alloc((size_t)1024 * 4096 * 2);           // 8 MB
    float*  bqkv  = (float*) alloc(3072 * 4);
    float2* alpha = (float2*)alloc((size_t)NB * NH * NS * 8);          // 1 MB
    bf16*   xb    = (bf16*)  alloc((size_t)8192 * 1024 * 2);           // 16 MB
    // 64 MB union: Qb|Kb|Vt|ctx live until g4; hb (g5/g6) aliases the whole block
    bf16*   ub    = (bf16*)  alloc((size_t)8192 * 4096 * 2);           // 64 MB
    bf16*   Qb    = ub;
    bf16*   Kb    = ub + (size_t)8192 * 1024;
    bf16*   Vt    = ub + (size_t)2 * 8192 * 1024;
    bf16*   ctx   = ub + (size_t)3 * 8192 * 1024;
    bf16*   hb    = ub;
    // 16 MB region shared by Vb (g1->vt_trans), t1b (g4->ln1), zb (g6->ln2)
    bf16*   t1b   = (bf16*)  alloc((size_t)8192 * 1024 * 2);           // 16 MB
    bf16*   Vb    = t1b;
    bf16*   zb    = t1b;
    bf16*   yb    = (bf16*)  alloc((size_t)8192 * 1024 * 2);           // 16 MB

    cvt_x<<<8192, 256, 0, stream>>>(x, xb, 8192 * 1024 / 4);
    prep_transpose<<<3072, 256, 0, stream>>>(Wq, Wk, Wv, Wo, W1, W2, wqkvT, WoT, W1T, W2T);
    prep_bias<<<12, 256, 0, stream>>>(bq, bk, bv, bqkv);
    g1_qkv<<<768, 512, 0, stream>>>(xb, wqkvT, bqkv, Qb, Kb, Vb);
    vt_trans<<<dim3(16, 128), 256, 0, stream>>>(Vb, Vt);
    g2_stats<<<dim3(8, 128), 256, 0, stream>>>(Qb, Kb, mask, alpha);
    g3_ctx<<<dim3(4, 128), 256, 0, stream>>>(Qb, Kb, Vt, alpha, ctx);
    g4_proj<<<256, 512, 0, stream>>>(ctx, WoT, bo, xb, t1b);
    ln_kernel<<<8192, 256, 0, stream>>>(t1b, yb, nullptr, ga, ba);
    g5_ffn1<<<512, 512, 0, stream>>>(yb, W1T, b1, hb);
    g6_ffn2<<<256, 512, 0, stream>>>(hb, W2T, b2, yb, zb);
    ln_kernel<<<8192, 256, 0, stream>>>(zb, nullptr, (float*)d_out, gf, bfb);
}

// Round 4
// 517.588 us; speedup vs baseline: 1.0392x; 1.0392x over previous
//
#include <hip/hip_runtime.h>
#include <hip/hip_bf16.h>

typedef __bf16 bf16;
typedef __bf16 bf16x8 __attribute__((ext_vector_type(8)));
typedef __bf16 bf16x4 __attribute__((ext_vector_type(4)));
typedef float  f32x4  __attribute__((ext_vector_type(4)));

#define NB 8
#define NS 1024
#define ND 1024
#define NH 16
#define NDK 64
#define NDFF 4096

static __device__ __forceinline__ f32x4 mfma16(bf16x8 a, bf16x8 b, f32x4 c) {
    return __builtin_amdgcn_mfma_f32_16x16x32_bf16(a, b, c, 0, 0, 0);
}

#define GLDS(g, l) __builtin_amdgcn_global_load_lds( \
    (const __attribute__((address_space(1))) void*)(g), \
    (__attribute__((address_space(3))) void*)(l), 16, 0, 0)

// fp32 -> bf16 elementwise (n4 = count/4)
__global__ __launch_bounds__(256) void cvt_x(const float* __restrict__ in,
                                             bf16* __restrict__ out, int n4)
{
    int idx = blockIdx.x * 256 + threadIdx.x;
    if (idx >= n4) return;
    float4 v = ((const float4*)in)[idx];
    bf16x4 o = { (bf16)v.x, (bf16)v.y, (bf16)v.z, (bf16)v.w };
    ((bf16x4*)out)[idx] = o;
}

// ---------------------------------------------------------------------------
// Weight prep: fp32 src -> bf16 BT layout [N][K]; fold 0.125 into Wq (exact).
// ---------------------------------------------------------------------------
__global__ __launch_bounds__(256) void prep_transpose(
    const float* __restrict__ Wq, const float* __restrict__ Wk, const float* __restrict__ Wv,
    const float* __restrict__ Wo, const float* __restrict__ W1, const float* __restrict__ W2,
    bf16* __restrict__ wqkvT, bf16* __restrict__ WoT,
    bf16* __restrict__ W1T, bf16* __restrict__ W2T)
{
    __shared__ float T[64][65];
    int bid = blockIdx.x;
    const float* src; bf16* dst; int srcLd, dstLd, tR, tC; bool scale = false;
    if (bid < 768) {                       // Wq/Wk/Wv: per-head [1024x64] -> [64x1024]
        int mat = bid >> 4, ty = bid & 15;
        int h = mat & 15, type = mat >> 4;
        const float* W = (type == 0) ? Wq : (type == 1 ? Wk : Wv);
        src = W + (size_t)h * ND * NDK;
        srcLd = NDK; tR = ty * 64; tC = 0;
        dst = wqkvT + ((size_t)type * 1024 + h * 64) * ND;
        dstLd = ND;
        scale = (type == 0);
    } else if (bid < 1024) {               // Wo [1024x1024] -> WoT
        int b2 = bid - 768; int ty = b2 >> 4, tx = b2 & 15;
        src = Wo; srcLd = ND; tR = ty * 64; tC = tx * 64; dst = WoT; dstLd = ND;
    } else if (bid < 2048) {               // W1 [1024x4096] -> W1T [4096x1024]
        int b2 = bid - 1024; int ty = b2 >> 6, tx = b2 & 63;
        src = W1; srcLd = NDFF; tR = ty * 64; tC = tx * 64; dst = W1T; dstLd = ND;
    } else {                               // W2 [4096x1024] -> W2T [1024x4096]
        int b2 = bid - 2048; int ty = b2 >> 4, tx = b2 & 15;
        src = W2; srcLd = ND; tR = ty * 64; tC = tx * 64; dst = W2T; dstLd = NDFF;
    }
    int t = threadIdx.x;
    int c0 = t & 63, r0 = t >> 6;
    #pragma unroll
    for (int rr = 0; rr < 16; rr++) {
        int row = rr * 4 + r0;
        T[row][c0] = src[(size_t)(tR + row) * srcLd + tC + c0];
    }
    __syncthreads();
    #pragma unroll
    for (int cc = 0; cc < 16; cc++) {
        int col = cc * 4 + r0;
        float v = T[c0][col];
        if (scale) v *= 0.125f;
        dst[(size_t)(tC + col) * dstLd + tR + c0] = (bf16)v;
    }
}

__global__ void prep_bias(const float* __restrict__ bq, const float* __restrict__ bk,
                          const float* __restrict__ bv, float* __restrict__ bqkv)
{
    int n = blockIdx.x * 256 + threadIdx.x;
    if (n >= 3072) return;
    int type = n >> 10, hk = n & 1023;
    const float* bb = (type == 0) ? bq : (type == 1 ? bk : bv);
    float v = bb[hk];
    if (type == 0) v *= 0.125f;
    bqkv[n] = v;
}

// ---------------------------------------------------------------------------
// Round-0 proven core: C[128x128] = A[M,K] * BT[N,K]^T. 4 waves 2x2, 256 thr.
// ---------------------------------------------------------------------------
__device__ __forceinline__ void gemm_bt_core(
    const bf16* __restrict__ A, const bf16* __restrict__ BT, int K,
    int rowBase, int colBase, f32x4 (&acc)[4][4], bf16* As, bf16* Bs)
{
    const int tid = threadIdx.x;
    const int lane = tid & 63, wid = tid >> 6;
    const int wr = (wid >> 1) * 64, wc = (wid & 1) * 64;
    const int lrow = lane & 15, lq = lane >> 4;
    const int srow = wid * 32 + (lane >> 3);
    const int gblk = (lane & 7) ^ ((lane >> 3) & 7);
    const bf16* Arow = A + (size_t)(rowBase + srow) * K + gblk * 8;
    const bf16* Brow = BT + (size_t)(colBase + srow) * K + gblk * 8;
    const int co0 = ((lq) ^ (lrow & 7)) * 8;
    const int co1 = ((4 + lq) ^ (lrow & 7)) * 8;
    f32x4 zz = {0.f, 0.f, 0.f, 0.f};
    #pragma unroll
    for (int i = 0; i < 4; i++)
        #pragma unroll
        for (int j = 0; j < 4; j++) acc[i][j] = zz;
    for (int k0 = 0; k0 < K; k0 += 64) {
        __syncthreads();
        #pragma unroll
        for (int it = 0; it < 4; it++)
            GLDS(Arow + (size_t)it * 8 * K + k0, As + (wid * 32 + it * 8) * 64);
        #pragma unroll
        for (int it = 0; it < 4; it++)
            GLDS(Brow + (size_t)it * 8 * K + k0, Bs + (wid * 32 + it * 8) * 64);
        __syncthreads();
        #pragma unroll
        for (int kh = 0; kh < 2; kh++) {
            const int co = kh ? co1 : co0;
            bf16x8 af[4], bfr[4];
            #pragma unroll
            for (int tt = 0; tt < 4; tt++) {
                af[tt]  = *(const bf16x8*)&As[(wr + tt * 16 + lrow) * 64 + co];
                bfr[tt] = *(const bf16x8*)&Bs[(wc + tt * 16 + lrow) * 64 + co];
            }
            #pragma unroll
            for (int i = 0; i < 4; i++)
                #pragma unroll
                for (int j = 0; j < 4; j++)
                    acc[i][j] = mfma16(af[i], bfr[j], acc[i][j]);
        }
    }
}

// ---------------------------------------------------------------------------
// 8-phase 256x256 core (m201 port): BK=64, 8 waves (2M x 4N), per-wave output
// 128x64. 2 K-tiles per iteration (set0: P1-4, set1: P5-8). Per phase:
// {ds_read held-frag subtile | stage 1 half-tile (2 gload_lds)} -> barrier ->
// setprio(1) + 16 MFMA + setprio(0) -> [vmcnt(4) @P4/P8] -> barrier.
// Frag schedule per K-tile: P1 reads A(ms0)+B(ns0) [12 b128], P2 B(ns1) [4],
// P3 A(ms1) [8], P4 none (held b0) -> each half-buffer's LAST read is mid-
// tile, so one freed half-stage slot opens per phase:
//   P1,P2: v.A -> set1 | P3,P4: (u+2).B -> set0 | P5,P6: (u+2).A -> set0 |
//   P7,P8: (v+2).B -> set1
// Queue bookkeeping: 12 loads outstanding at each wait -> vmcnt(4) retires
// exactly the tile needed next, leaves 2 half-tiles (issued 1-2 phases ago)
// in flight. Never drains to 0 in steady state (T4). No manual lgkmcnt, no
// sched_barrier (compiler's fine-grained lgkm interleave is near-optimal;
// pinning it was R2's mistake). Two barriers/phase close the read-retire vs
// stage-overwrite race deterministically. XOR-8 swizzle as before.
// ---------------------------------------------------------------------------
__device__ __forceinline__ void gemm8p(
    const bf16* __restrict__ A, const bf16* __restrict__ BT, int K,
    int rowBase, int colBase, f32x4 (&acc)[8][4], bf16* As, bf16* Bs)
{
    constexpr int SETSZ = 256 * 64;
    const int tid = threadIdx.x, lane = tid & 63, wid = tid >> 6;
    const int wm = wid >> 2, wn = wid & 3;
    const int lrow = lane & 15, lq = lane >> 4;
    const int s8 = lane >> 3, gblk = (lane & 7) ^ s8;
    const int co0 = (lq ^ (lrow & 7)) * 8;
    const int co1 = ((4 + lq) ^ (lrow & 7)) * 8;
    f32x4 zz = {0.f, 0.f, 0.f, 0.f};
    #pragma unroll
    for (int i = 0; i < 8; i++)
        #pragma unroll
        for (int j = 0; j < 4; j++) acc[i][j] = zz;
    const bf16* Ag = A  + (size_t)(rowBase + wid * 8 + s8) * K + gblk * 8;
    const bf16* Bg = BT + (size_t)(colBase + wid * 8 + s8) * K + gblk * 8;

#define SG_A(kt, set, h) do { \
    GLDS(Ag + (size_t)((h) * 128) * K + (kt) * 64, \
         As + (set) * SETSZ + ((h) * 128 + wid * 8) * 64); \
    GLDS(Ag + (size_t)((h) * 128 + 64) * K + (kt) * 64, \
         As + (set) * SETSZ + ((h) * 128 + 64 + wid * 8) * 64); \
} while (0)
#define SG_B(kt, set, h) do { \
    GLDS(Bg + (size_t)((h) * 128) * K + (kt) * 64, \
         Bs + (set) * SETSZ + ((h) * 128 + wid * 8) * 64); \
    GLDS(Bg + (size_t)((h) * 128 + 64) * K + (kt) * 64, \
         Bs + (set) * SETSZ + ((h) * 128 + 64 + wid * 8) * 64); \
} while (0)
#define RD_A(dst, base, ms) do { _Pragma("unroll") for (int i_ = 0; i_ < 4; i_++) { \
    int ro_ = (wm * 128 + (ms) * 64 + i_ * 16 + lrow) * 64; \
    dst[i_][0] = *(const bf16x8*)&(base)[ro_ + co0]; \
    dst[i_][1] = *(const bf16x8*)&(base)[ro_ + co1]; } } while (0)
#define RD_B(dst, base, ns) do { _Pragma("unroll") for (int j_ = 0; j_ < 2; j_++) { \
    int ro_ = (wn * 64 + (ns) * 32 + j_ * 16 + lrow) * 64; \
    dst[j_][0] = *(const bf16x8*)&(base)[ro_ + co0]; \
    dst[j_][1] = *(const bf16x8*)&(base)[ro_ + co1]; } } while (0)
#define CL8(av, bv, ms, ns) do { \
    __builtin_amdgcn_s_setprio(1); \
    _Pragma("unroll") for (int i_ = 0; i_ < 4; i_++) \
    _Pragma("unroll") for (int j_ = 0; j_ < 2; j_++) { \
        acc[(ms) * 4 + i_][(ns) * 2 + j_] = \
            mfma16(av[i_][0], bv[j_][0], acc[(ms) * 4 + i_][(ns) * 2 + j_]); \
        acc[(ms) * 4 + i_][(ns) * 2 + j_] = \
            mfma16(av[i_][1], bv[j_][1], acc[(ms) * 4 + i_][(ns) * 2 + j_]); } \
    __builtin_amdgcn_s_setprio(0); \
} while (0)
#define BAR8 __builtin_amdgcn_s_barrier()
#define VM4 asm volatile("s_waitcnt vmcnt(4)" ::: "memory")
#define VM0 asm volatile("s_waitcnt vmcnt(0)" ::: "memory")

    const int nt = K >> 6, nIter = nt >> 1;
    // prologue: t0.B, t0.A, t1.B (12 loads); vmcnt(4) -> t0 landed, t1.B in flight
    SG_B(0, 0, 0); SG_B(0, 0, 1);
    SG_A(0, 0, 0); SG_A(0, 0, 1);
    SG_B(1, 1, 0); SG_B(1, 1, 1);
    VM4; BAR8;
    const bf16* A0b = As;           const bf16* B0b = Bs;
    const bf16* A1b = As + SETSZ;   const bf16* B1b = Bs + SETSZ;
    for (int J = 0; J < nIter; ++J) {
        const int v = 2 * J + 1;
        const bool pf = (J + 1 < nIter);
        bf16x8 a0[4][2], a1[4][2], b0[2][2], b1[2][2];
        // ---- K-tile u = 2J (set0) ----
        // P1
        RD_A(a0, A0b, 0); RD_B(b0, B0b, 0);
        SG_A(v, 1, 0);
        BAR8; CL8(a0, b0, 0, 0); BAR8;
        // P2
        RD_B(b1, B0b, 1);
        SG_A(v, 1, 1);
        BAR8; CL8(a0, b1, 0, 1); BAR8;
        // P3
        RD_A(a1, A0b, 1);
        if (pf) SG_B(v + 1, 0, 0);
        BAR8; CL8(a1, b1, 1, 1); BAR8;
        // P4 (no reads; b0 held since P1)
        if (pf) SG_B(v + 1, 0, 1);
        BAR8; CL8(a1, b0, 1, 0);
        if (pf) { VM4; } else { VM0; }
        BAR8;
        // ---- K-tile v = 2J+1 (set1) ----
        // P5
        RD_A(a0, A1b, 0); RD_B(b0, B1b, 0);
        if (pf) SG_A(v + 1, 0, 0);
        BAR8; CL8(a0, b0, 0, 0); BAR8;
        // P6
        RD_B(b1, B1b, 1);
        if (pf) SG_A(v + 1, 0, 1);
        BAR8; CL8(a0, b1, 0, 1); BAR8;
        // P7
        RD_A(a1, A1b, 1);
        if (pf) SG_B(v + 2, 1, 0);
        BAR8; CL8(a1, b1, 1, 1); BAR8;
        // P8
        if (pf) SG_B(v + 2, 1, 1);
        BAR8; CL8(a1, b0, 1, 0);
        if (pf) { VM4; } else { VM0; }
        BAR8;
    }
#undef SG_A
#undef SG_B
#undef RD_A
#undef RD_B
#undef CL8
#undef BAR8
#undef VM4
#undef VM0
}

// ---------------------------------------------------------------------------
// Core B (round-2 proven for g6): 128x256, BK=64, 8 waves, 2 phases x 16
// MFMA, TRIPLE-buf LDS (144 KiB): stage tile t+2 during tile t, vmcnt(6).
// ---------------------------------------------------------------------------
__device__ __forceinline__ void gemmB_core(
    const bf16* __restrict__ A, const bf16* __restrict__ BT, int K,
    int rowBase, int colBase, f32x4 (&acc)[4][4], bf16* As, bf16* Bs)
{
    constexpr int ABUF = 128 * 64, BBUF = 256 * 64;
    const int tid = threadIdx.x, lane = tid & 63, wid = tid >> 6;
    const int wm = wid >> 2, wn = wid & 3;
    const int lrow = lane & 15, lq = lane >> 4;
    const int srow = lane >> 3, gblk = (lane & 7) ^ srow;
    const int co0 = (lq ^ (lrow & 7)) * 8;
    const int co1 = ((4 + lq) ^ (lrow & 7)) * 8;
    f32x4 zz = {0.f, 0.f, 0.f, 0.f};
    #pragma unroll
    for (int i = 0; i < 4; i++)
        #pragma unroll
        for (int j = 0; j < 4; j++) acc[i][j] = zz;
    const bf16* Ag = A  + (size_t)(rowBase + wid * 8 + srow) * K + gblk * 8;
    const bf16* Bg = BT + (size_t)(colBase + wid * 8 + srow) * K + gblk * 8;

#define SGA2(kt, bi, rr) GLDS(Ag + (size_t)(kt) * 64 + (size_t)(rr) * 64 * K, \
                              As + (bi) * ABUF + ((rr) * 64 + wid * 8) * 64)
#define SGB2(kt, bi, rr) GLDS(Bg + (size_t)(kt) * 64 + (size_t)(rr) * 64 * K, \
                              Bs + (bi) * BBUF + ((rr) * 64 + wid * 8) * 64)
#define RDA2() do { _Pragma("unroll") for (int i_ = 0; i_ < 4; i_++) { \
    int ro_ = (wm * 64 + i_ * 16 + lrow) * 64; \
    af[i_][0] = *(const bf16x8*)&Ab[ro_ + co0]; \
    af[i_][1] = *(const bf16x8*)&Ab[ro_ + co1]; } } while (0)
#define RDB2(dst, NS_) do { _Pragma("unroll") for (int j_ = 0; j_ < 2; j_++) { \
    int ro_ = (wn * 64 + (NS_) * 32 + j_ * 16 + lrow) * 64; \
    dst[j_][0] = *(const bf16x8*)&Bb[ro_ + co0]; \
    dst[j_][1] = *(const bf16x8*)&Bb[ro_ + co1]; } } while (0)
#define CLUSTER_B(bfx, JO) do { \
    __builtin_amdgcn_s_barrier(); \
    asm volatile("s_waitcnt lgkmcnt(0)" ::: "memory"); \
    __builtin_amdgcn_sched_barrier(0); \
    __builtin_amdgcn_s_setprio(1); \
    _Pragma("unroll") \
    for (int i_ = 0; i_ < 4; i_++) \
        _Pragma("unroll") \
        for (int j_ = 0; j_ < 2; j_++) { \
            acc[i_][(JO) + j_] = mfma16(af[i_][0], bfx[j_][0], acc[i_][(JO) + j_]); \
            acc[i_][(JO) + j_] = mfma16(af[i_][1], bfx[j_][1], acc[i_][(JO) + j_]); \
        } \
    __builtin_amdgcn_s_setprio(0); \
} while (0)

    const int nt = K >> 6;
    SGA2(0, 0, 0); SGA2(0, 0, 1);
    SGB2(0, 0, 0); SGB2(0, 0, 1); SGB2(0, 0, 2); SGB2(0, 0, 3);
    SGA2(1, 1, 0); SGA2(1, 1, 1);
    SGB2(1, 1, 0); SGB2(1, 1, 1); SGB2(1, 1, 2); SGB2(1, 1, 3);
    asm volatile("s_waitcnt vmcnt(6)" ::: "memory");
    __builtin_amdgcn_s_barrier();

    int ci = 0, si = 2;
    for (int t = 0; t < nt; ++t) {
        const bf16* Ab = As + ci * ABUF;
        const bf16* Bb = Bs + ci * BBUF;
        const bool pf = (t + 2 < nt);
        bf16x8 af[4][2], bf0[2][2], bf1[2][2];
        RDA2(); RDB2(bf0, 0);
        if (pf) { SGA2(t + 2, si, 0); SGA2(t + 2, si, 1); SGB2(t + 2, si, 0); SGB2(t + 2, si, 1); }
        CLUSTER_B(bf0, 0);
        __builtin_amdgcn_s_barrier();
        RDB2(bf1, 1);
        if (pf) { SGB2(t + 2, si, 2); SGB2(t + 2, si, 3); }
        CLUSTER_B(bf1, 2);
        if (pf)                asm volatile("s_waitcnt vmcnt(6)" ::: "memory");
        else if (t + 1 < nt)   asm volatile("s_waitcnt vmcnt(0)" ::: "memory");
        __builtin_amdgcn_s_barrier();
        ci = (ci == 2) ? 0 : ci + 1;
        si = (si == 2) ? 0 : si + 1;
    }
#undef SGA2
#undef SGB2
#undef RDA2
#undef RDB2
#undef CLUSTER_B
}

// G1: xb @ [Wq|Wk|Wv] + bias; 8-phase core, BN=256, grid 384 (32x12)
__global__ __launch_bounds__(512, 2) void g1_qkv(
    const bf16* __restrict__ x, const bf16* __restrict__ wqkvT, const float* __restrict__ bqkv,
    bf16* __restrict__ Q, bf16* __restrict__ Kb, bf16* __restrict__ Vb)
{
    __shared__ bf16 As[2 * 256 * 64], Bs[2 * 256 * 64];   // 128 KiB
    f32x4 acc[8][4];
    int g = blockIdx.x;
    int sw = (g & 7) * 48 + (g >> 3);                     // 384 % 8 == 0
    int bm = sw / 12, bn = sw % 12;
    int rowBase = bm * 256, colBase = bn * 256;
    gemm8p(x, wqkvT, ND, rowBase, colBase, acc, As, Bs);
    const int tid = threadIdx.x, lane = tid & 63, wid = tid >> 6;
    const int wm = wid >> 2, wn = wid & 3, lrow = lane & 15, lq = lane >> 4;
    #pragma unroll
    for (int j = 0; j < 4; j++) {
        int gcol = colBase + wn * 64 + j * 16 + lrow;
        float bias = bqkv[gcol];
        int type = gcol >> 10, h = (gcol >> 6) & 15, kk = gcol & 63;
        bf16* dst = (type == 0) ? Q : (type == 1 ? Kb : Vb);
        #pragma unroll
        for (int i = 0; i < 8; i++) {
            #pragma unroll
            for (int r = 0; r < 4; r++) {
                int grow = rowBase + wm * 128 + i * 16 + lq * 4 + r;
                int b = grow >> 10, s = grow & 1023;
                dst[((size_t)(b * NH + h) * NS + s) * NDK + kk] = (bf16)(acc[i][j][r] + bias);
            }
        }
    }
}

// Vb [bh][s][kk] -> Vt [bh][kk][s]  (LDS-tiled transpose)
__global__ __launch_bounds__(256) void vt_trans(
    const bf16* __restrict__ Vb, bf16* __restrict__ Vt)
{
    __shared__ bf16 T[64 * 72];
    int bh = blockIdx.y, s0 = blockIdx.x * 64;
    const bf16* src = Vb + ((size_t)bh * NS + s0) * NDK;
    int tid = threadIdx.x;
    #pragma unroll
    for (int it = 0; it < 2; it++) {
        int g = tid + it * 256;
        int row = g >> 3, c = (g & 7) * 8;
        *(bf16x8*)&T[row * 72 + c] = *(const bf16x8*)&src[row * NDK + c];
    }
    __syncthreads();
    #pragma unroll
    for (int it = 0; it < 2; it++) {
        int g = tid + it * 256;
        int kk = g >> 3, sc = (g & 7) * 8;
        bf16x8 v;
        #pragma unroll
        for (int t = 0; t < 8; t++) v[t] = T[(sc + t) * 72 + kk];
        *(bf16x8*)&Vt[((size_t)bh * NDK + kk) * NS + s0 + sc] = v;
    }
}

// G2: per-key-column coefficients: unmasked (1/sum_i exp(s_ij), 0); masked (0, 1/1024).
__global__ __launch_bounds__(256) void g2_stats(
    const bf16* __restrict__ Q, const bf16* __restrict__ Kb,
    const int* __restrict__ mask, float2* __restrict__ alpha)
{
    __shared__ bf16 Qs[128 * 64];
    int bh = blockIdx.y, b = bh >> 4;
    int jBase = blockIdx.x * 128;
    const bf16* Kp = Kb + (size_t)bh * NS * NDK;
    const bf16* Qp = Q + (size_t)bh * NS * NDK;
    const int tid = threadIdx.x, lane = tid & 63, wid = tid >> 6;
    const int lrow = lane & 15, lq = lane >> 4;
    bf16x8 kf[2][2];
    #pragma unroll
    for (int jt = 0; jt < 2; jt++)
        #pragma unroll
        for (int kh = 0; kh < 2; kh++)
            kf[jt][kh] = *(const bf16x8*)&Kp[(size_t)(jBase + wid * 32 + jt * 16 + lrow) * NDK + kh * 32 + lq * 8];
    const int srow = lane >> 3;
    const int gblk = (lane & 7) ^ srow;
    float Lacc[2][4];
    #pragma unroll
    for (int jt = 0; jt < 2; jt++)
        #pragma unroll
        for (int r = 0; r < 4; r++) Lacc[jt][r] = 0.f;
    f32x4 zz = {0.f, 0.f, 0.f, 0.f};
    for (int i0 = 0; i0 < NS; i0 += 128) {
        __syncthreads();
        #pragma unroll
        for (int it = 0; it < 4; it++)
            GLDS(Qp + (size_t)(i0 + wid * 32 + it * 8 + srow) * NDK + gblk * 8,
                 Qs + (wid * 32 + it * 8) * 64);
        __syncthreads();
        #pragma unroll
        for (int it = 0; it < 8; it++) {
            bf16x8 qb[2];
            #pragma unroll
            for (int kh = 0; kh < 2; kh++)
                qb[kh] = *(const bf16x8*)&Qs[(it * 16 + lrow) * 64 + ((kh * 4 + lq) ^ (lrow & 7)) * 8];
            #pragma unroll
            for (int jt = 0; jt < 2; jt++) {
                f32x4 s = mfma16(kf[jt][0], qb[0], zz);
                s = mfma16(kf[jt][1], qb[1], s);
                #pragma unroll
                for (int r = 0; r < 4; r++) Lacc[jt][r] += __expf(s[r]);
            }
        }
    }
    #pragma unroll
    for (int jt = 0; jt < 2; jt++) {
        #pragma unroll
        for (int r = 0; r < 4; r++) {
            float v = Lacc[jt][r];
            v += __shfl_xor(v, 1); v += __shfl_xor(v, 2);
            v += __shfl_xor(v, 4); v += __shfl_xor(v, 8);
            if (lrow == 0) {
                int j = jBase + wid * 32 + jt * 16 + lq * 4 + r;
                int m = mask[b * NS + j];
                float2 ac;
                ac.x = m ? 1.f / v : 0.f;
                ac.y = m ? 0.f : (1.f / 1024.f);
                alpha[(size_t)bh * NS + j] = ac;
            }
        }
    }
}

// G3: ctx[i][kk] = sum_j (a_j*exp(s_ij)+c_j) * v[j][kk]
__global__ __launch_bounds__(256) void g3_ctx(
    const bf16* __restrict__ Q, const bf16* __restrict__ Kb, const bf16* __restrict__ Vt,
    const float2* __restrict__ alpha, bf16* __restrict__ ctx)
{
    __shared__ bf16 Ks[64 * 64];       // 8 KB
    __shared__ bf16 Vs[64 * 64];       // 8 KB
    __shared__ bf16 Ps[4 * 64 * 64];   // 32 KB, per-wave 8KB, XOR-swizzled
    int bh = blockIdx.y, iBase = blockIdx.x * 256;
    int b = bh >> 4, h = bh & 15;
    const bf16* Qp = Q + (size_t)bh * NS * NDK;
    const bf16* Kp = Kb + (size_t)bh * NS * NDK;
    const bf16* Vp = Vt + (size_t)bh * NDK * NS;
    const float2* al = alpha + (size_t)bh * NS;
    const int tid = threadIdx.x, lane = tid & 63, wid = tid >> 6;
    const int lrow = lane & 15, lq = lane >> 4;
    const int iw = iBase + wid * 64;
    bf16x8 qf[4][2];
    #pragma unroll
    for (int it = 0; it < 4; it++)
        #pragma unroll
        for (int kh = 0; kh < 2; kh++)
            qf[it][kh] = *(const bf16x8*)&Qp[(size_t)(iw + it * 16 + lrow) * NDK + kh * 32 + lq * 8];
    const int srow = lane >> 3;
    const int gblk = (lane & 7) ^ srow;
    f32x4 cacc[4][4];
    f32x4 zz = {0.f, 0.f, 0.f, 0.f};
    #pragma unroll
    for (int it = 0; it < 4; it++)
        #pragma unroll
        for (int kt = 0; kt < 4; kt++) cacc[it][kt] = zz;
    bf16* Pw = Ps + wid * 64 * 64;
    for (int j0 = 0; j0 < NS; j0 += 64) {
        __syncthreads();
        #pragma unroll
        for (int it = 0; it < 2; it++)
            GLDS(Kp + (size_t)(j0 + wid * 16 + it * 8 + srow) * NDK + gblk * 8,
                 Ks + (wid * 16 + it * 8) * 64);
        #pragma unroll
        for (int it = 0; it < 2; it++)
            GLDS(Vp + (size_t)(wid * 16 + it * 8 + srow) * NS + j0 + gblk * 8,
                 Vs + (wid * 16 + it * 8) * 64);
        __syncthreads();
        bf16x8 kb[4][2];
        #pragma unroll
        for (int jt = 0; jt < 4; jt++)
            #pragma unroll
            for (int kh = 0; kh < 2; kh++)
                kb[jt][kh] = *(const bf16x8*)&Ks[(jt * 16 + lrow) * 64 + ((kh * 4 + lq) ^ (lrow & 7)) * 8];
        #pragma unroll
        for (int jt = 0; jt < 4; jt++) {
            float2 acj[4];
            #pragma unroll
            for (int r = 0; r < 4; r++) acj[r] = al[j0 + jt * 16 + lq * 4 + r];
            #pragma unroll
            for (int it = 0; it < 4; it++) {
                f32x4 s = mfma16(kb[jt][0], qf[it][0], zz);
                s = mfma16(kb[jt][1], qf[it][1], s);
                bf16x4 pv;
                #pragma unroll
                for (int r = 0; r < 4; r++)
                    pv[r] = (bf16)(acj[r].x * __expf(s[r]) + acj[r].y);
                int i = it * 16 + lrow;
                int jb = jt * 2 + (lq >> 1);
                *(bf16x4*)&Pw[i * 64 + ((jb ^ (i & 7)) * 8) + (lq & 1) * 4] = pv;
            }
        }
        bf16x8 vb[4][2];
        #pragma unroll
        for (int kt = 0; kt < 4; kt++)
            #pragma unroll
            for (int kh = 0; kh < 2; kh++)
                vb[kt][kh] = *(const bf16x8*)&Vs[(kt * 16 + lrow) * 64 + ((kh * 4 + lq) ^ (lrow & 7)) * 8];
        #pragma unroll
        for (int it = 0; it < 4; it++) {
            bf16x8 pa[2];
            #pragma unroll
            for (int kh = 0; kh < 2; kh++)
                pa[kh] = *(const bf16x8*)&Pw[(it * 16 + lrow) * 64 + ((kh * 4 + lq) ^ (lrow & 7)) * 8];
            #pragma unroll
            for (int kt = 0; kt < 4; kt++) {
                cacc[it][kt] = mfma16(pa[0], vb[kt][0], cacc[it][kt]);
                cacc[it][kt] = mfma16(pa[1], vb[kt][1], cacc[it][kt]);
            }
        }
    }
    #pragma unroll
    for (int kt = 0; kt < 4; kt++) {
        int col = h * NDK + kt * 16 + lrow;
        #pragma unroll
        for (int it = 0; it < 4; it++) {
            #pragma unroll
            for (int r = 0; r < 4; r++) {
                int i = iw + it * 16 + lq * 4 + r;
                ctx[(size_t)(b * NS + i) * ND + col] = (bf16)cacc[it][kt][r];
            }
        }
    }
}

// G4: t1b = bf16(ctx @ Wo + bo + xb)   (round-0 128^2 core)
__global__ __launch_bounds__(256) void g4_proj(
    const bf16* __restrict__ ctx, const bf16* __restrict__ WoT, const float* __restrict__ bo,
    const bf16* __restrict__ xb, bf16* __restrict__ t1b)
{
    __shared__ bf16 As[128 * 64], Bs[128 * 64];
    f32x4 acc[4][4];
    int rowBase = blockIdx.x * 128, colBase = blockIdx.y * 128;
    gemm_bt_core(ctx, WoT, ND, rowBase, colBase, acc, As, Bs);
    const int tid = threadIdx.x, lane = tid & 63, wid = tid >> 6;
    const int wr = (wid >> 1) * 64, wc = (wid & 1) * 64, lrow = lane & 15, lq = lane >> 4;
    #pragma unroll
    for (int j = 0; j < 4; j++) {
        int gcol = colBase + wc + j * 16 + lrow;
        float bias = bo[gcol];
        #pragma unroll
        for (int i = 0; i < 4; i++) {
            #pragma unroll
            for (int r = 0; r < 4; r++) {
                int grow = rowBase + wr + i * 16 + lq * 4 + r;
                float v = acc[i][j][r] + bias + (float)xb[(size_t)grow * ND + gcol];
                t1b[(size_t)grow * ND + gcol] = (bf16)v;
            }
        }
    }
}

// G5: hb = relu(yb @ W1 + b1)   8-phase core, grid 512 (32x16)
__global__ __launch_bounds__(512, 2) void g5_ffn1(
    const bf16* __restrict__ y, const bf16* __restrict__ W1T, const float* __restrict__ b1,
    bf16* __restrict__ hb)
{
    __shared__ bf16 As[2 * 256 * 64], Bs[2 * 256 * 64];   // 128 KiB
    f32x4 acc[8][4];
    int g = blockIdx.x;
    int sw = (g & 7) * 64 + (g >> 3);
    int bm = sw >> 4, bn = sw & 15;
    int rowBase = bm * 256, colBase = bn * 256;
    gemm8p(y, W1T, ND, rowBase, colBase, acc, As, Bs);
    const int tid = threadIdx.x, lane = tid & 63, wid = tid >> 6;
    const int wm = wid >> 2, wn = wid & 3, lrow = lane & 15, lq = lane >> 4;
    #pragma unroll
    for (int j = 0; j < 4; j++) {
        int gcol = colBase + wn * 64 + j * 16 + lrow;
        float bias = b1[gcol];
        #pragma unroll
        for (int i = 0; i < 8; i++) {
            #pragma unroll
            for (int r = 0; r < 4; r++) {
                int grow = rowBase + wm * 128 + i * 16 + lq * 4 + r;
                float v = fmaxf(acc[i][j][r] + bias, 0.f);
                hb[(size_t)grow * NDFF + gcol] = (bf16)v;
            }
        }
    }
}

// G6: zb = bf16(hb @ W2 + b2 + yb)   core B, grid 256, K=4096
__global__ __launch_bounds__(512, 2) void g6_ffn2(
    const bf16* __restrict__ hb, const bf16* __restrict__ W2T, const float* __restrict__ b2,
    const bf16* __restrict__ yb, bf16* __restrict__ zb)
{
    __shared__ bf16 As[3 * 128 * 64], Bs[3 * 256 * 64];   // 144 KiB
    f32x4 acc[4][4];
    int g = blockIdx.x;
    int sw = (g & 7) * 32 + (g >> 3);
    int bm = sw >> 2, bn = sw & 3;
    int rowBase = bm * 128, colBase = bn * 256;
    gemmB_core(hb, W2T, NDFF, rowBase, colBase, acc, As, Bs);
    const int tid = threadIdx.x, lane = tid & 63, wid = tid >> 6;
    const int wm = wid >> 2, wn = wid & 3, lrow = lane & 15, lq = lane >> 4;
    #pragma unroll
    for (int j = 0; j < 4; j++) {
        int gcol = colBase + wn * 64 + j * 16 + lrow;
        float bias = b2[gcol];
        #pragma unroll
        for (int i = 0; i < 4; i++) {
            #pragma unroll
            for (int r = 0; r < 4; r++) {
                int grow = rowBase + wm * 64 + i * 16 + lq * 4 + r;
                float v = acc[i][j][r] + bias + (float)yb[(size_t)grow * ND + gcol];
                zb[(size_t)grow * ND + gcol] = (bf16)v;
            }
        }
    }
}

// Row LayerNorm over D=1024, bf16 in; writes bf16 (outb) and/or fp32 (outf)
__global__ __launch_bounds__(256) void ln_kernel(
    const bf16* __restrict__ in, bf16* __restrict__ outb, float* __restrict__ outf,
    const float* __restrict__ g, const float* __restrict__ bb)
{
    int row = blockIdx.x, tid = threadIdx.x;
    const bf16* p = in + (size_t)row * ND;
    bf16x4 v4 = *(const bf16x4*)&p[tid * 4];
    float vv[4] = {(float)v4[0], (float)v4[1], (float)v4[2], (float)v4[3]};
    float s = vv[0] + vv[1] + vv[2] + vv[3];
    float q = vv[0]*vv[0] + vv[1]*vv[1] + vv[2]*vv[2] + vv[3]*vv[3];
    #pragma unroll
    for (int m = 1; m < 64; m <<= 1) { s += __shfl_xor(s, m); q += __shfl_xor(q, m); }
    __shared__ float rs[4], rq[4];
    int wid = tid >> 6, lane = tid & 63;
    if (lane == 0) { rs[wid] = s; rq[wid] = q; }
    __syncthreads();
    s = rs[0] + rs[1] + rs[2] + rs[3];
    q = rq[0] + rq[1] + rq[2] + rq[3];
    float mean = s * (1.f / 1024.f);
    float var = q * (1.f / 1024.f) - mean * mean;
    float rstd = 1.f / sqrtf(var + 1e-5f);
    float4 of;
    bf16x4 ob;
    #pragma unroll
    for (int k = 0; k < 4; k++) {
        int col = tid * 4 + k;
        float yv = (vv[k] - mean) * rstd * g[col] + bb[col];
        ((float*)&of)[k] = yv;
        ob[k] = (bf16)yv;
    }
    if (outb) *(bf16x4*)&outb[(size_t)row * ND + tid * 4] = ob;
    if (outf) ((float4*)(outf + (size_t)row * ND))[tid] = of;
}

// ---------------------------------------------------------------------------
extern "C" void kernel_launch(void* const* d_in, const int* in_sizes, int n_in,
                              void* d_out, int out_size, void* d_ws, size_t ws_size,
                              hipStream_t stream)
{
    const float* x    = (const float*)d_in[0];
    const int*   mask = (const int*)d_in[1];
    const float* Wq   = (const float*)d_in[2];
    const float* bq   = (const float*)d_in[3];
    const float* Wk   = (const float*)d_in[4];
    const float* bk   = (const float*)d_in[5];
    const float* Wv   = (const float*)d_in[6];
    const float* bv   = (const float*)d_in[7];
    const float* Wo   = (const float*)d_in[8];
    const float* bo   = (const float*)d_in[9];
    const float* ga   = (const float*)d_in[10];
    const float* ba   = (const float*)d_in[11];
    const float* W1   = (const float*)d_in[12];
    const float* b1   = (const float*)d_in[13];
    const float* W2   = (const float*)d_in[14];
    const float* b2   = (const float*)d_in[15];
    const float* gf   = (const float*)d_in[16];
    const float* bfb  = (const float*)d_in[17];

    size_t off = 0;
    auto alloc = [&](size_t n) { char* p = (char*)d_ws + off; off += (n + 255) & ~(size_t)255; return (void*)p; };
    bf16*   wqkvT = (bf16*)  alloc((size_t)3072 * 1024 * 2);           // 6 MB
    bf16*   WoT   = (bf16*)  alloc((size_t)1024 * 1024 * 2);           // 2 MB
    bf16*   W1T   = (bf16*)  alloc((size_t)4096 * 1024 * 2);           // 8 MB
    bf16*   W2T   = (bf16*)  alloc((size_t)1024 * 4096 * 2);           // 8 MB
    float*  bqkv  = (float*) alloc(3072 * 4);
    float2* alpha = (float2*)alloc((size_t)NB * NH * NS * 8);          // 1 MB
    bf16*   xb    = (bf16*)  alloc((size_t)8192 * 1024 * 2);           // 16 MB
    // 64 MB union: Qb|Kb|Vt|ctx live until g4; hb (g5/g6) aliases the whole block
    bf16*   ub    = (bf16*)  alloc((size_t)8192 * 4096 * 2);           // 64 MB
    bf16*   Qb    = ub;
    bf16*   Kb    = ub + (size_t)8192 * 1024;
    bf16*   Vt    = ub + (size_t)2 * 8192 * 1024;
    bf16*   ctx   = ub + (size_t)3 * 8192 * 1024;
    bf16*   hb    = ub;
    // 16 MB region shared by Vb (g1->vt_trans), t1b (g4->ln1), zb (g6->ln2)
    bf16*   t1b   = (bf16*)  alloc((size_t)8192 * 1024 * 2);           // 16 MB
    bf16*   Vb    = t1b;
    bf16*   zb    = t1b;
    bf16*   yb    = (bf16*)  alloc((size_t)8192 * 1024 * 2);           // 16 MB

    cvt_x<<<8192, 256, 0, stream>>>(x, xb, 8192 * 1024 / 4);
    prep_transpose<<<3072, 256, 0, stream>>>(Wq, Wk, Wv, Wo, W1, W2, wqkvT, WoT, W1T, W2T);
    prep_bias<<<12, 256, 0, stream>>>(bq, bk, bv, bqkv);
    g1_qkv<<<384, 512, 0, stream>>>(xb, wqkvT, bqkv, Qb, Kb, Vb);
    vt_trans<<<dim3(16, 128), 256, 0, stream>>>(Vb, Vt);
    g2_stats<<<dim3(8, 128), 256, 0, stream>>>(Qb, Kb, mask, alpha);
    g3_ctx<<<dim3(4, 128), 256, 0, stream>>>(Qb, Kb, Vt, alpha, ctx);
    g4_proj<<<dim3(64, 8), 256, 0, stream>>>(ctx, WoT, bo, xb, t1b);
    ln_kernel<<<8192, 256, 0, stream>>>(t1b, yb, nullptr, ga, ba);
    g5_ffn1<<<512, 512, 0, stream>>>(yb, W1T, b1, hb);
    g6_ffn2<<<256, 512, 0, stream>>>(hb, W2T, b2, yb, zb);
    ln_kernel<<<8192, 256, 0, stream>>>(zb, nullptr, (float*)d_out, gf, bfb);
}

// Round 7
// 507.815 us; speedup vs baseline: 1.0592x; 1.0192x over previous
//
#include <hip/hip_runtime.h>
#include <hip/hip_bf16.h>

typedef __bf16 bf16;
typedef __bf16 bf16x8 __attribute__((ext_vector_type(8)));
typedef __bf16 bf16x4 __attribute__((ext_vector_type(4)));
typedef float  f32x4  __attribute__((ext_vector_type(4)));

#define NB 8
#define NS 1024
#define ND 1024
#define NH 16
#define NDK 64
#define NDFF 4096

static __device__ __forceinline__ f32x4 mfma16(bf16x8 a, bf16x8 b, f32x4 c) {
    return __builtin_amdgcn_mfma_f32_16x16x32_bf16(a, b, c, 0, 0, 0);
}

#define GLDS(g, l) __builtin_amdgcn_global_load_lds( \
    (const __attribute__((address_space(1))) void*)(g), \
    (__attribute__((address_space(3))) void*)(l), 16, 0, 0)

// fp32 -> bf16 elementwise (n4 = count/4)
__global__ __launch_bounds__(256) void cvt_x(const float* __restrict__ in,
                                             bf16* __restrict__ out, int n4)
{
    int idx = blockIdx.x * 256 + threadIdx.x;
    if (idx >= n4) return;
    float4 v = ((const float4*)in)[idx];
    bf16x4 o = { (bf16)v.x, (bf16)v.y, (bf16)v.z, (bf16)v.w };
    ((bf16x4*)out)[idx] = o;
}

// ---------------------------------------------------------------------------
// Weight prep: fp32 src -> bf16 BT layout [N][K]; fold 0.125 into Wq (exact).
// ---------------------------------------------------------------------------
__global__ __launch_bounds__(256) void prep_transpose(
    const float* __restrict__ Wq, const float* __restrict__ Wk, const float* __restrict__ Wv,
    const float* __restrict__ Wo, const float* __restrict__ W1, const float* __restrict__ W2,
    bf16* __restrict__ wqkvT, bf16* __restrict__ WoT,
    bf16* __restrict__ W1T, bf16* __restrict__ W2T)
{
    __shared__ float T[64][65];
    int bid = blockIdx.x;
    const float* src; bf16* dst; int srcLd, dstLd, tR, tC; bool scale = false;
    if (bid < 768) {                       // Wq/Wk/Wv: per-head [1024x64] -> [64x1024]
        int mat = bid >> 4, ty = bid & 15;
        int h = mat & 15, type = mat >> 4;
        const float* W = (type == 0) ? Wq : (type == 1 ? Wk : Wv);
        src = W + (size_t)h * ND * NDK;
        srcLd = NDK; tR = ty * 64; tC = 0;
        dst = wqkvT + ((size_t)type * 1024 + h * 64) * ND;
        dstLd = ND;
        scale = (type == 0);
    } else if (bid < 1024) {               // Wo [1024x1024] -> WoT
        int b2 = bid - 768; int ty = b2 >> 4, tx = b2 & 15;
        src = Wo; srcLd = ND; tR = ty * 64; tC = tx * 64; dst = WoT; dstLd = ND;
    } else if (bid < 2048) {               // W1 [1024x4096] -> W1T [4096x1024]
        int b2 = bid - 1024; int ty = b2 >> 6, tx = b2 & 63;
        src = W1; srcLd = NDFF; tR = ty * 64; tC = tx * 64; dst = W1T; dstLd = ND;
    } else {                               // W2 [4096x1024] -> W2T [1024x4096]
        int b2 = bid - 2048; int ty = b2 >> 4, tx = b2 & 15;
        src = W2; srcLd = ND; tR = ty * 64; tC = tx * 64; dst = W2T; dstLd = NDFF;
    }
    int t = threadIdx.x;
    int c0 = t & 63, r0 = t >> 6;
    #pragma unroll
    for (int rr = 0; rr < 16; rr++) {
        int row = rr * 4 + r0;
        T[row][c0] = src[(size_t)(tR + row) * srcLd + tC + c0];
    }
    __syncthreads();
    #pragma unroll
    for (int cc = 0; cc < 16; cc++) {
        int col = cc * 4 + r0;
        float v = T[c0][col];
        if (scale) v *= 0.125f;
        dst[(size_t)(tC + col) * dstLd + tR + c0] = (bf16)v;
    }
}

__global__ void prep_bias(const float* __restrict__ bq, const float* __restrict__ bk,
                          const float* __restrict__ bv, float* __restrict__ bqkv)
{
    int n = blockIdx.x * 256 + threadIdx.x;
    if (n >= 3072) return;
    int type = n >> 10, hk = n & 1023;
    const float* bb = (type == 0) ? bq : (type == 1 ? bk : bv);
    float v = bb[hk];
    if (type == 0) v *= 0.125f;
    bqkv[n] = v;
}

// ---------------------------------------------------------------------------
// mask_scan: per batch, stable partition of key axis. newpos[b*NS+j] = rank
// among unmasked (if mask=1) else U_b + rank among masked. Ucnt[b] = U_b.
// Softmax is over the QUERY axis, so masked columns are exactly uniform
// 1/1024 -> their PV contribution is a per-(b,h) constant vector (cvec).
// ---------------------------------------------------------------------------
__global__ __launch_bounds__(256) void mask_scan(const int* __restrict__ mask,
                                                 int* __restrict__ newpos,
                                                 int* __restrict__ Ucnt)
{
    int b = blockIdx.x, t = threadIdx.x;
    __shared__ int sums[256];
    __shared__ int scans[257];
    const int* mb = mask + b * NS;
    int m[4], s = 0;
    #pragma unroll
    for (int k = 0; k < 4; k++) { m[k] = (mb[t * 4 + k] != 0) ? 1 : 0; s += m[k]; }
    sums[t] = s;
    __syncthreads();
    if (t == 0) {
        int acc = 0;
        for (int i = 0; i < 256; i++) { scans[i] = acc; acc += sums[i]; }
        scans[256] = acc;
        Ucnt[b] = acc;
    }
    __syncthreads();
    int U = scans[256];
    int p = scans[t];
    #pragma unroll
    for (int k = 0; k < 4; k++) {
        int j = t * 4 + k;
        newpos[b * NS + j] = m[k] ? p : U + (j - p);
        p += m[k];
    }
}

// cvec[bh][kk] = (1/1024) * sum over masked (compacted s >= U_b) of Vb[bh][s][kk]
__global__ __launch_bounds__(256) void cvec_kernel(const bf16* __restrict__ Vb,
                                                   const int* __restrict__ Ucnt,
                                                   float* __restrict__ cvec)
{
    int bh = blockIdx.x, b = bh >> 4;
    int U = Ucnt[b];
    int t = threadIdx.x, kk = t & 63, ss = t >> 6;
    const bf16* Vp = Vb + (size_t)bh * NS * NDK;
    float a = 0.f;
    for (int s = U + ss; s < NS; s += 4) a += (float)Vp[s * NDK + kk];
    __shared__ float red[4][64];
    red[ss][kk] = a;
    __syncthreads();
    if (ss == 0)
        cvec[bh * 64 + kk] = (red[0][kk] + red[1][kk] + red[2][kk] + red[3][kk]) * (1.f / 1024.f);
}

// ---------------------------------------------------------------------------
// Round-0 proven core: C[128x128] = A[M,K] * BT[N,K]^T. 4 waves 2x2, 256 thr.
// ---------------------------------------------------------------------------
__device__ __forceinline__ void gemm_bt_core(
    const bf16* __restrict__ A, const bf16* __restrict__ BT, int K,
    int rowBase, int colBase, f32x4 (&acc)[4][4], bf16* As, bf16* Bs)
{
    const int tid = threadIdx.x;
    const int lane = tid & 63, wid = tid >> 6;
    const int wr = (wid >> 1) * 64, wc = (wid & 1) * 64;
    const int lrow = lane & 15, lq = lane >> 4;
    const int srow = wid * 32 + (lane >> 3);
    const int gblk = (lane & 7) ^ ((lane >> 3) & 7);
    const bf16* Arow = A + (size_t)(rowBase + srow) * K + gblk * 8;
    const bf16* Brow = BT + (size_t)(colBase + srow) * K + gblk * 8;
    const int co0 = ((lq) ^ (lrow & 7)) * 8;
    const int co1 = ((4 + lq) ^ (lrow & 7)) * 8;
    f32x4 zz = {0.f, 0.f, 0.f, 0.f};
    #pragma unroll
    for (int i = 0; i < 4; i++)
        #pragma unroll
        for (int j = 0; j < 4; j++) acc[i][j] = zz;
    for (int k0 = 0; k0 < K; k0 += 64) {
        __syncthreads();
        #pragma unroll
        for (int it = 0; it < 4; it++)
            GLDS(Arow + (size_t)it * 8 * K + k0, As + (wid * 32 + it * 8) * 64);
        #pragma unroll
        for (int it = 0; it < 4; it++)
            GLDS(Brow + (size_t)it * 8 * K + k0, Bs + (wid * 32 + it * 8) * 64);
        __syncthreads();
        #pragma unroll
        for (int kh = 0; kh < 2; kh++) {
            const int co = kh ? co1 : co0;
            bf16x8 af[4], bfr[4];
            #pragma unroll
            for (int tt = 0; tt < 4; tt++) {
                af[tt]  = *(const bf16x8*)&As[(wr + tt * 16 + lrow) * 64 + co];
                bfr[tt] = *(const bf16x8*)&Bs[(wc + tt * 16 + lrow) * 64 + co];
            }
            #pragma unroll
            for (int i = 0; i < 4; i++)
                #pragma unroll
                for (int j = 0; j < 4; j++)
                    acc[i][j] = mfma16(af[i], bfr[j], acc[i][j]);
        }
    }
}

// ---------------------------------------------------------------------------
// 8-phase 256x256 core (measured best for g5 in R4).
// ---------------------------------------------------------------------------
__device__ __forceinline__ void gemm8p(
    const bf16* __restrict__ A, const bf16* __restrict__ BT, int K,
    int rowBase, int colBase, f32x4 (&acc)[8][4], bf16* As, bf16* Bs)
{
    constexpr int SETSZ = 256 * 64;
    const int tid = threadIdx.x, lane = tid & 63, wid = tid >> 6;
    const int wm = wid >> 2, wn = wid & 3;
    const int lrow = lane & 15, lq = lane >> 4;
    const int s8 = lane >> 3, gblk = (lane & 7) ^ s8;
    const int co0 = (lq ^ (lrow & 7)) * 8;
    const int co1 = ((4 + lq) ^ (lrow & 7)) * 8;
    f32x4 zz = {0.f, 0.f, 0.f, 0.f};
    #pragma unroll
    for (int i = 0; i < 8; i++)
        #pragma unroll
        for (int j = 0; j < 4; j++) acc[i][j] = zz;
    const bf16* Ag = A  + (size_t)(rowBase + wid * 8 + s8) * K + gblk * 8;
    const bf16* Bg = BT + (size_t)(colBase + wid * 8 + s8) * K + gblk * 8;

#define SG_A(kt, set, h) do { \
    GLDS(Ag + (size_t)((h) * 128) * K + (kt) * 64, \
         As + (set) * SETSZ + ((h) * 128 + wid * 8) * 64); \
    GLDS(Ag + (size_t)((h) * 128 + 64) * K + (kt) * 64, \
         As + (set) * SETSZ + ((h) * 128 + 64 + wid * 8) * 64); \
} while (0)
#define SG_B(kt, set, h) do { \
    GLDS(Bg + (size_t)((h) * 128) * K + (kt) * 64, \
         Bs + (set) * SETSZ + ((h) * 128 + wid * 8) * 64); \
    GLDS(Bg + (size_t)((h) * 128 + 64) * K + (kt) * 64, \
         Bs + (set) * SETSZ + ((h) * 128 + 64 + wid * 8) * 64); \
} while (0)
#define RD_A(dst, base, ms) do { _Pragma("unroll") for (int i_ = 0; i_ < 4; i_++) { \
    int ro_ = (wm * 128 + (ms) * 64 + i_ * 16 + lrow) * 64; \
    dst[i_][0] = *(const bf16x8*)&(base)[ro_ + co0]; \
    dst[i_][1] = *(const bf16x8*)&(base)[ro_ + co1]; } } while (0)
#define RD_B(dst, base, ns) do { _Pragma("unroll") for (int j_ = 0; j_ < 2; j_++) { \
    int ro_ = (wn * 64 + (ns) * 32 + j_ * 16 + lrow) * 64; \
    dst[j_][0] = *(const bf16x8*)&(base)[ro_ + co0]; \
    dst[j_][1] = *(const bf16x8*)&(base)[ro_ + co1]; } } while (0)
#define CL8(av, bv, ms, ns) do { \
    __builtin_amdgcn_s_setprio(1); \
    _Pragma("unroll") for (int i_ = 0; i_ < 4; i_++) \
    _Pragma("unroll") for (int j_ = 0; j_ < 2; j_++) { \
        acc[(ms) * 4 + i_][(ns) * 2 + j_] = \
            mfma16(av[i_][0], bv[j_][0], acc[(ms) * 4 + i_][(ns) * 2 + j_]); \
        acc[(ms) * 4 + i_][(ns) * 2 + j_] = \
            mfma16(av[i_][1], bv[j_][1], acc[(ms) * 4 + i_][(ns) * 2 + j_]); } \
    __builtin_amdgcn_s_setprio(0); \
} while (0)
#define BAR8 __builtin_amdgcn_s_barrier()
#define VM4 asm volatile("s_waitcnt vmcnt(4)" ::: "memory")
#define VM0 asm volatile("s_waitcnt vmcnt(0)" ::: "memory")

    const int nt = K >> 6, nIter = nt >> 1;
    SG_B(0, 0, 0); SG_B(0, 0, 1);
    SG_A(0, 0, 0); SG_A(0, 0, 1);
    SG_B(1, 1, 0); SG_B(1, 1, 1);
    VM4; BAR8;
    const bf16* A0b = As;           const bf16* B0b = Bs;
    const bf16* A1b = As + SETSZ;   const bf16* B1b = Bs + SETSZ;
    for (int J = 0; J < nIter; ++J) {
        const int v = 2 * J + 1;
        const bool pf = (J + 1 < nIter);
        bf16x8 a0[4][2], a1[4][2], b0[2][2], b1[2][2];
        // ---- K-tile u = 2J (set0) ----
        RD_A(a0, A0b, 0); RD_B(b0, B0b, 0);
        SG_A(v, 1, 0);
        BAR8; CL8(a0, b0, 0, 0); BAR8;
        RD_B(b1, B0b, 1);
        SG_A(v, 1, 1);
        BAR8; CL8(a0, b1, 0, 1); BAR8;
        RD_A(a1, A0b, 1);
        if (pf) SG_B(v + 1, 0, 0);
        BAR8; CL8(a1, b1, 1, 1); BAR8;
        if (pf) SG_B(v + 1, 0, 1);
        BAR8; CL8(a1, b0, 1, 0);
        if (pf) { VM4; } else { VM0; }
        BAR8;
        // ---- K-tile v = 2J+1 (set1) ----
        RD_A(a0, A1b, 0); RD_B(b0, B1b, 0);
        if (pf) SG_A(v + 1, 0, 0);
        BAR8; CL8(a0, b0, 0, 0); BAR8;
        RD_B(b1, B1b, 1);
        if (pf) SG_A(v + 1, 0, 1);
        BAR8; CL8(a0, b1, 0, 1); BAR8;
        RD_A(a1, A1b, 1);
        if (pf) SG_B(v + 2, 1, 0);
        BAR8; CL8(a1, b1, 1, 1); BAR8;
        if (pf) SG_B(v + 2, 1, 1);
        BAR8; CL8(a1, b0, 1, 0);
        if (pf) { VM4; } else { VM0; }
        BAR8;
    }
#undef SG_A
#undef SG_B
#undef RD_A
#undef RD_B
#undef CL8
#undef BAR8
#undef VM4
#undef VM0
}

// ---------------------------------------------------------------------------
// Core B (measured best for g6): 128x256, BK=64, 8 waves, 2 phases x 16 MFMA,
// TRIPLE-buf LDS (144 KiB): stage tile t+2 during tile t, vmcnt(6).
// ---------------------------------------------------------------------------
__device__ __forceinline__ void gemmB_core(
    const bf16* __restrict__ A, const bf16* __restrict__ BT, int K,
    int rowBase, int colBase, f32x4 (&acc)[4][4], bf16* As, bf16* Bs)
{
    constexpr int ABUF = 128 * 64, BBUF = 256 * 64;
    const int tid = threadIdx.x, lane = tid & 63, wid = tid >> 6;
    const int wm = wid >> 2, wn = wid & 3;
    const int lrow = lane & 15, lq = lane >> 4;
    const int srow = lane >> 3, gblk = (lane & 7) ^ srow;
    const int co0 = (lq ^ (lrow & 7)) * 8;
    const int co1 = ((4 + lq) ^ (lrow & 7)) * 8;
    f32x4 zz = {0.f, 0.f, 0.f, 0.f};
    #pragma unroll
    for (int i = 0; i < 4; i++)
        #pragma unroll
        for (int j = 0; j < 4; j++) acc[i][j] = zz;
    const bf16* Ag = A  + (size_t)(rowBase + wid * 8 + srow) * K + gblk * 8;
    const bf16* Bg = BT + (size_t)(colBase + wid * 8 + srow) * K + gblk * 8;

#define SGA2(kt, bi, rr) GLDS(Ag + (size_t)(kt) * 64 + (size_t)(rr) * 64 * K, \
                              As + (bi) * ABUF + ((rr) * 64 + wid * 8) * 64)
#define SGB2(kt, bi, rr) GLDS(Bg + (size_t)(kt) * 64 + (size_t)(rr) * 64 * K, \
                              Bs + (bi) * BBUF + ((rr) * 64 + wid * 8) * 64)
#define RDA2() do { _Pragma("unroll") for (int i_ = 0; i_ < 4; i_++) { \
    int ro_ = (wm * 64 + i_ * 16 + lrow) * 64; \
    af[i_][0] = *(const bf16x8*)&Ab[ro_ + co0]; \
    af[i_][1] = *(const bf16x8*)&Ab[ro_ + co1]; } } while (0)
#define RDB2(dst, NS_) do { _Pragma("unroll") for (int j_ = 0; j_ < 2; j_++) { \
    int ro_ = (wn * 64 + (NS_) * 32 + j_ * 16 + lrow) * 64; \
    dst[j_][0] = *(const bf16x8*)&Bb[ro_ + co0]; \
    dst[j_][1] = *(const bf16x8*)&Bb[ro_ + co1]; } } while (0)
#define CLUSTER_B(bfx, JO) do { \
    __builtin_amdgcn_s_barrier(); \
    asm volatile("s_waitcnt lgkmcnt(0)" ::: "memory"); \
    __builtin_amdgcn_sched_barrier(0); \
    __builtin_amdgcn_s_setprio(1); \
    _Pragma("unroll") \
    for (int i_ = 0; i_ < 4; i_++) \
        _Pragma("unroll") \
        for (int j_ = 0; j_ < 2; j_++) { \
            acc[i_][(JO) + j_] = mfma16(af[i_][0], bfx[j_][0], acc[i_][(JO) + j_]); \
            acc[i_][(JO) + j_] = mfma16(af[i_][1], bfx[j_][1], acc[i_][(JO) + j_]); \
        } \
    __builtin_amdgcn_s_setprio(0); \
} while (0)

    const int nt = K >> 6;
    SGA2(0, 0, 0); SGA2(0, 0, 1);
    SGB2(0, 0, 0); SGB2(0, 0, 1); SGB2(0, 0, 2); SGB2(0, 0, 3);
    SGA2(1, 1, 0); SGA2(1, 1, 1);
    SGB2(1, 1, 0); SGB2(1, 1, 1); SGB2(1, 1, 2); SGB2(1, 1, 3);
    asm volatile("s_waitcnt vmcnt(6)" ::: "memory");
    __builtin_amdgcn_s_barrier();

    int ci = 0, si = 2;
    for (int t = 0; t < nt; ++t) {
        const bf16* Ab = As + ci * ABUF;
        const bf16* Bb = Bs + ci * BBUF;
        const bool pf = (t + 2 < nt);
        bf16x8 af[4][2], bf0[2][2], bf1[2][2];
        RDA2(); RDB2(bf0, 0);
        if (pf) { SGA2(t + 2, si, 0); SGA2(t + 2, si, 1); SGB2(t + 2, si, 0); SGB2(t + 2, si, 1); }
        CLUSTER_B(bf0, 0);
        __builtin_amdgcn_s_barrier();
        RDB2(bf1, 1);
        if (pf) { SGB2(t + 2, si, 2); SGB2(t + 2, si, 3); }
        CLUSTER_B(bf1, 2);
        if (pf)                asm volatile("s_waitcnt vmcnt(6)" ::: "memory");
        else if (t + 1 < nt)   asm volatile("s_waitcnt vmcnt(0)" ::: "memory");
        __builtin_amdgcn_s_barrier();
        ci = (ci == 2) ? 0 : ci + 1;
        si = (si == 2) ? 0 : si + 1;
    }
#undef SGA2
#undef SGB2
#undef RDA2
#undef RDB2
#undef CLUSTER_B
}

// G1: xb @ [Wq|Wk|Wv] + bias; Q row-major, K/V rows written through newpos
// (compacted: unmasked first). 128^2 core, grid (64,24) = 1536 blocks.
__global__ __launch_bounds__(256) void g1_qkv(
    const bf16* __restrict__ x, const bf16* __restrict__ wqkvT, const float* __restrict__ bqkv,
    const int* __restrict__ newpos,
    bf16* __restrict__ Q, bf16* __restrict__ Kb, bf16* __restrict__ Vb)
{
    __shared__ bf16 As[128 * 64], Bs[128 * 64];
    f32x4 acc[4][4];
    int rowBase = blockIdx.x * 128, colBase = blockIdx.y * 128;
    gemm_bt_core(x, wqkvT, ND, rowBase, colBase, acc, As, Bs);
    const int tid = threadIdx.x, lane = tid & 63, wid = tid >> 6;
    const int wr = (wid >> 1) * 64, wc = (wid & 1) * 64, lrow = lane & 15, lq = lane >> 4;
    const int type = colBase >> 10;   // block is entirely within one of Q/K/V
    int spv[4][4];
    if (type != 0) {
        #pragma unroll
        for (int i = 0; i < 4; i++)
            #pragma unroll
            for (int r = 0; r < 4; r++) {
                int grow = rowBase + wr + i * 16 + lq * 4 + r;
                spv[i][r] = newpos[grow];   // == newpos[b*NS + s]
            }
    }
    #pragma unroll
    for (int j = 0; j < 4; j++) {
        int gcol = colBase + wc + j * 16 + lrow;
        float bias = bqkv[gcol];
        int h = (gcol >> 6) & 15, kk = gcol & 63;
        bf16* dst = (type == 0) ? Q : (type == 1 ? Kb : Vb);
        #pragma unroll
        for (int i = 0; i < 4; i++) {
            #pragma unroll
            for (int r = 0; r < 4; r++) {
                int grow = rowBase + wr + i * 16 + lq * 4 + r;
                int b = grow >> 10;
                int s = (type == 0) ? (grow & 1023) : spv[i][r];
                dst[((size_t)(b * NH + h) * NS + s) * NDK + kk] = (bf16)(acc[i][j][r] + bias);
            }
        }
    }
}

// Vb [bh][s][kk] -> Vt [bh][kk][s]  (LDS-tiled transpose; compacted order)
__global__ __launch_bounds__(256) void vt_trans(
    const bf16* __restrict__ Vb, bf16* __restrict__ Vt)
{
    __shared__ bf16 T[64 * 72];
    int bh = blockIdx.y, s0 = blockIdx.x * 64;
    const bf16* src = Vb + ((size_t)bh * NS + s0) * NDK;
    int tid = threadIdx.x;
    #pragma unroll
    for (int it = 0; it < 2; it++) {
        int g = tid + it * 256;
        int row = g >> 3, c = (g & 7) * 8;
        *(bf16x8*)&T[row * 72 + c] = *(const bf16x8*)&src[row * NDK + c];
    }
    __syncthreads();
    #pragma unroll
    for (int it = 0; it < 2; it++) {
        int g = tid + it * 256;
        int kk = g >> 3, sc = (g & 7) * 8;
        bf16x8 v;
        #pragma unroll
        for (int t = 0; t < 8; t++) v[t] = T[(sc + t) * 72 + kk];
        *(bf16x8*)&Vt[((size_t)bh * NDK + kk) * NS + s0 + sc] = v;
    }
}

// G2: column-sum coefficients over COMPACTED keys. Only tiles with jBase < U_b
// do work; alpha = (1/L_j, 0) for j < U_b else (0,0). Masked keys handled by
// cvec in g3 -- no mask read here.
__global__ __launch_bounds__(256) void g2_stats(
    const bf16* __restrict__ Q, const bf16* __restrict__ Kb,
    const int* __restrict__ Ucnt, float2* __restrict__ alpha)
{
    __shared__ bf16 Qs[128 * 64];
    int bh = blockIdx.y, b = bh >> 4;
    int jBase = blockIdx.x * 128;
    int U = Ucnt[b];
    const int tid = threadIdx.x;
    if (jBase >= U) {                      // whole tile masked/padded
        if (tid < 128) {
            float2 z; z.x = 0.f; z.y = 0.f;
            alpha[(size_t)bh * NS + jBase + tid] = z;
        }
        return;
    }
    const bf16* Kp = Kb + (size_t)bh * NS * NDK;
    const bf16* Qp = Q + (size_t)bh * NS * NDK;
    const int lane = tid & 63, wid = tid >> 6;
    const int lrow = lane & 15, lq = lane >> 4;
    bf16x8 kf[2][2];
    #pragma unroll
    for (int jt = 0; jt < 2; jt++)
        #pragma unroll
        for (int kh = 0; kh < 2; kh++)
            kf[jt][kh] = *(const bf16x8*)&Kp[(size_t)(jBase + wid * 32 + jt * 16 + lrow) * NDK + kh * 32 + lq * 8];
    const int srow = lane >> 3;
    const int gblk = (lane & 7) ^ srow;
    float Lacc[2][4];
    #pragma unroll
    for (int jt = 0; jt < 2; jt++)
        #pragma unroll
        for (int r = 0; r < 4; r++) Lacc[jt][r] = 0.f;
    f32x4 zz = {0.f, 0.f, 0.f, 0.f};
    for (int i0 = 0; i0 < NS; i0 += 128) {
        __syncthreads();
        #pragma unroll
        for (int it = 0; it < 4; it++)
            GLDS(Qp + (size_t)(i0 + wid * 32 + it * 8 + srow) * NDK + gblk * 8,
                 Qs + (wid * 32 + it * 8) * 64);
        __syncthreads();
        #pragma unroll
        for (int it = 0; it < 8; it++) {
            bf16x8 qb[2];
            #pragma unroll
            for (int kh = 0; kh < 2; kh++)
                qb[kh] = *(const bf16x8*)&Qs[(it * 16 + lrow) * 64 + ((kh * 4 + lq) ^ (lrow & 7)) * 8];
            #pragma unroll
            for (int jt = 0; jt < 2; jt++) {
                f32x4 s = mfma16(kf[jt][0], qb[0], zz);
                s = mfma16(kf[jt][1], qb[1], s);
                #pragma unroll
                for (int r = 0; r < 4; r++) Lacc[jt][r] += __expf(s[r]);
            }
        }
    }
    #pragma unroll
    for (int jt = 0; jt < 2; jt++) {
        #pragma unroll
        for (int r = 0; r < 4; r++) {
            float v = Lacc[jt][r];
            v += __shfl_xor(v, 1); v += __shfl_xor(v, 2);
            v += __shfl_xor(v, 4); v += __shfl_xor(v, 8);
            if (lrow == 0) {
                int j = jBase + wid * 32 + jt * 16 + lq * 4 + r;
                float2 ac;
                ac.x = (j < U) ? 1.f / v : 0.f;
                ac.y = 0.f;
                alpha[(size_t)bh * NS + j] = ac;
            }
        }
    }
}

// G3: ctx[i][kk] = sum_{compacted j < Ur} a_j*exp(s_ij) * v[j][kk] + cvec[kk]
__global__ __launch_bounds__(256) void g3_ctx(
    const bf16* __restrict__ Q, const bf16* __restrict__ Kb, const bf16* __restrict__ Vt,
    const float2* __restrict__ alpha, const int* __restrict__ Ucnt,
    const float* __restrict__ cvec, bf16* __restrict__ ctx)
{
    __shared__ bf16 Ks[64 * 64];       // 8 KB
    __shared__ bf16 Vs[64 * 64];       // 8 KB
    __shared__ bf16 Ps[4 * 64 * 64];   // 32 KB, per-wave 8KB, XOR-swizzled
    int bh = blockIdx.y, iBase = blockIdx.x * 256;
    int b = bh >> 4, h = bh & 15;
    int U = Ucnt[b];
    int Ur = (U + 63) & ~63;           // j-tiles only over compacted unmasked keys
    const bf16* Qp = Q + (size_t)bh * NS * NDK;
    const bf16* Kp = Kb + (size_t)bh * NS * NDK;
    const bf16* Vp = Vt + (size_t)bh * NDK * NS;
    const float2* al = alpha + (size_t)bh * NS;
    const int tid = threadIdx.x, lane = tid & 63, wid = tid >> 6;
    const int lrow = lane & 15, lq = lane >> 4;
    const int iw = iBase + wid * 64;
    bf16x8 qf[4][2];
    #pragma unroll
    for (int it = 0; it < 4; it++)
        #pragma unroll
        for (int kh = 0; kh < 2; kh++)
            qf[it][kh] = *(const bf16x8*)&Qp[(size_t)(iw + it * 16 + lrow) * NDK + kh * 32 + lq * 8];
    const int srow = lane >> 3;
    const int gblk = (lane & 7) ^ srow;
    f32x4 cacc[4][4];
    f32x4 zz = {0.f, 0.f, 0.f, 0.f};
    #pragma unroll
    for (int it = 0; it < 4; it++)
        #pragma unroll
        for (int kt = 0; kt < 4; kt++) cacc[it][kt] = zz;
    bf16* Pw = Ps + wid * 64 * 64;
    for (int j0 = 0; j0 < Ur; j0 += 64) {
        __syncthreads();
        #pragma unroll
        for (int it = 0; it < 2; it++)
            GLDS(Kp + (size_t)(j0 + wid * 16 + it * 8 + srow) * NDK + gblk * 8,
                 Ks + (wid * 16 + it * 8) * 64);
        #pragma unroll
        for (int it = 0; it < 2; it++)
            GLDS(Vp + (size_t)(wid * 16 + it * 8 + srow) * NS + j0 + gblk * 8,
                 Vs + (wid * 16 + it * 8) * 64);
        __syncthreads();
        bf16x8 kb[4][2];
        #pragma unroll
        for (int jt = 0; jt < 4; jt++)
            #pragma unroll
            for (int kh = 0; kh < 2; kh++)
                kb[jt][kh] = *(const bf16x8*)&Ks[(jt * 16 + lrow) * 64 + ((kh * 4 + lq) ^ (lrow & 7)) * 8];
        #pragma unroll
        for (int jt = 0; jt < 4; jt++) {
            float2 acj[4];
            #pragma unroll
            for (int r = 0; r < 4; r++) acj[r] = al[j0 + jt * 16 + lq * 4 + r];
            #pragma unroll
            for (int it = 0; it < 4; it++) {
                f32x4 s = mfma16(kb[jt][0], qf[it][0], zz);
                s = mfma16(kb[jt][1], qf[it][1], s);
                bf16x4 pv;
                #pragma unroll
                for (int r = 0; r < 4; r++)
                    pv[r] = (bf16)(acj[r].x * __expf(s[r]) + acj[r].y);
                int i = it * 16 + lrow;
                int jb = jt * 2 + (lq >> 1);
                *(bf16x4*)&Pw[i * 64 + ((jb ^ (i & 7)) * 8) + (lq & 1) * 4] = pv;
            }
        }
        bf16x8 vb[4][2];
        #pragma unroll
        for (int kt = 0; kt < 4; kt++)
            #pragma unroll
            for (int kh = 0; kh < 2; kh++)
                vb[kt][kh] = *(const bf16x8*)&Vs[(kt * 16 + lrow) * 64 + ((kh * 4 + lq) ^ (lrow & 7)) * 8];
        #pragma unroll
        for (int it = 0; it < 4; it++) {
            bf16x8 pa[2];
            #pragma unroll
            for (int kh = 0; kh < 2; kh++)
                pa[kh] = *(const bf16x8*)&Pw[(it * 16 + lrow) * 64 + ((kh * 4 + lq) ^ (lrow & 7)) * 8];
            #pragma unroll
            for (int kt = 0; kt < 4; kt++) {
                cacc[it][kt] = mfma16(pa[0], vb[kt][0], cacc[it][kt]);
                cacc[it][kt] = mfma16(pa[1], vb[kt][1], cacc[it][kt]);
            }
        }
    }
    #pragma unroll
    for (int kt = 0; kt < 4; kt++) {
        int col = h * NDK + kt * 16 + lrow;
        float cv = cvec[bh * 64 + kt * 16 + lrow];
        #pragma unroll
        for (int it = 0; it < 4; it++) {
            #pragma unroll
            for (int r = 0; r < 4; r++) {
                int i = iw + it * 16 + lq * 4 + r;
                ctx[(size_t)(b * NS + i) * ND + col] = (bf16)(cacc[it][kt][r] + cv);
            }
        }
    }
}

// G4: t1b = bf16(ctx @ Wo + bo + xb)   (128^2 core)
__global__ __launch_bounds__(256) void g4_proj(
    const bf16* __restrict__ ctx, const bf16* __restrict__ WoT, const float* __restrict__ bo,
    const bf16* __restrict__ xb, bf16* __restrict__ t1b)
{
    __shared__ bf16 As[128 * 64], Bs[128 * 64];
    f32x4 acc[4][4];
    int rowBase = blockIdx.x * 128, colBase = blockIdx.y * 128;
    gemm_bt_core(ctx, WoT, ND, rowBase, colBase, acc, As, Bs);
    const int tid = threadIdx.x, lane = tid & 63, wid = tid >> 6;
    const int wr = (wid >> 1) * 64, wc = (wid & 1) * 64, lrow = lane & 15, lq = lane >> 4;
    #pragma unroll
    for (int j = 0; j < 4; j++) {
        int gcol = colBase + wc + j * 16 + lrow;
        float bias = bo[gcol];
        #pragma unroll
        for (int i = 0; i < 4; i++) {
            #pragma unroll
            for (int r = 0; r < 4; r++) {
                int grow = rowBase + wr + i * 16 + lq * 4 + r;
                float v = acc[i][j][r] + bias + (float)xb[(size_t)grow * ND + gcol];
                t1b[(size_t)grow * ND + gcol] = (bf16)v;
            }
        }
    }
}

// G5: hb = relu(yb @ W1 + b1)   8-phase core, grid 512 (32x16)
__global__ __launch_bounds__(512, 2) void g5_ffn1(
    const bf16* __restrict__ y, const bf16* __restrict__ W1T, const float* __restrict__ b1,
    bf16* __restrict__ hb)
{
    __shared__ bf16 As[2 * 256 * 64], Bs[2 * 256 * 64];   // 128 KiB
    f32x4 acc[8][4];
    int g = blockIdx.x;
    int sw = (g & 7) * 64 + (g >> 3);
    int bm = sw >> 4, bn = sw & 15;
    int rowBase = bm * 256, colBase = bn * 256;
    gemm8p(y, W1T, ND, rowBase, colBase, acc, As, Bs);
    const int tid = threadIdx.x, lane = tid & 63, wid = tid >> 6;
    const int wm = wid >> 2, wn = wid & 3, lrow = lane & 15, lq = lane >> 4;
    #pragma unroll
    for (int j = 0; j < 4; j++) {
        int gcol = colBase + wn * 64 + j * 16 + lrow;
        float bias = b1[gcol];
        #pragma unroll
        for (int i = 0; i < 8; i++) {
            #pragma unroll
            for (int r = 0; r < 4; r++) {
                int grow = rowBase + wm * 128 + i * 16 + lq * 4 + r;
                float v = fmaxf(acc[i][j][r] + bias, 0.f);
                hb[(size_t)grow * NDFF + gcol] = (bf16)v;
            }
        }
    }
}

// G6: zb = bf16(hb @ W2 + b2 + yb)   core B, grid 256, K=4096
__global__ __launch_bounds__(512, 2) void g6_ffn2(
    const bf16* __restrict__ hb, const bf16* __restrict__ W2T, const float* __restrict__ b2,
    const bf16* __restrict__ yb, bf16* __restrict__ zb)
{
    __shared__ bf16 As[3 * 128 * 64], Bs[3 * 256 * 64];   // 144 KiB
    f32x4 acc[4][4];
    int g = blockIdx.x;
    int sw = (g & 7) * 32 + (g >> 3);
    int bm = sw >> 2, bn = sw & 3;
    int rowBase = bm * 128, colBase = bn * 256;
    gemmB_core(hb, W2T, NDFF, rowBase, colBase, acc, As, Bs);
    const int tid = threadIdx.x, lane = tid & 63, wid = tid >> 6;
    const int wm = wid >> 2, wn = wid & 3, lrow = lane & 15, lq = lane >> 4;
    #pragma unroll
    for (int j = 0; j < 4; j++) {
        int gcol = colBase + wn * 64 + j * 16 + lrow;
        float bias = b2[gcol];
        #pragma unroll
        for (int i = 0; i < 4; i++) {
            #pragma unroll
            for (int r = 0; r < 4; r++) {
                int grow = rowBase + wm * 64 + i * 16 + lq * 4 + r;
                float v = acc[i][j][r] + bias + (float)yb[(size_t)grow * ND + gcol];
                zb[(size_t)grow * ND + gcol] = (bf16)v;
            }
        }
    }
}

// Row LayerNorm over D=1024, bf16 in; writes bf16 (outb) and/or fp32 (outf)
__global__ __launch_bounds__(256) void ln_kernel(
    const bf16* __restrict__ in, bf16* __restrict__ outb, float* __restrict__ outf,
    const float* __restrict__ g, const float* __restrict__ bb)
{
    int row = blockIdx.x, tid = threadIdx.x;
    const bf16* p = in + (size_t)row * ND;
    bf16x4 v4 = *(const bf16x4*)&p[tid * 4];
    float vv[4] = {(float)v4[0], (float)v4[1], (float)v4[2], (float)v4[3]};
    float s = vv[0] + vv[1] + vv[2] + vv[3];
    float q = vv[0]*vv[0] + vv[1]*vv[1] + vv[2]*vv[2] + vv[3]*vv[3];
    #pragma unroll
    for (int m = 1; m < 64; m <<= 1) { s += __shfl_xor(s, m); q += __shfl_xor(q, m); }
    __shared__ float rs[4], rq[4];
    int wid = tid >> 6, lane = tid & 63;
    if (lane == 0) { rs[wid] = s; rq[wid] = q; }
    __syncthreads();
    s = rs[0] + rs[1] + rs[2] + rs[3];
    q = rq[0] + rq[1] + rq[2] + rq[3];
    float mean = s * (1.f / 1024.f);
    float var = q * (1.f / 1024.f) - mean * mean;
    float rstd = 1.f / sqrtf(var + 1e-5f);
    float4 of;
    bf16x4 ob;
    #pragma unroll
    for (int k = 0; k < 4; k++) {
        int col = tid * 4 + k;
        float yv = (vv[k] - mean) * rstd * g[col] + bb[col];
        ((float*)&of)[k] = yv;
        ob[k] = (bf16)yv;
    }
    if (outb) *(bf16x4*)&outb[(size_t)row * ND + tid * 4] = ob;
    if (outf) ((float4*)(outf + (size_t)row * ND))[tid] = of;
}

// ---------------------------------------------------------------------------
extern "C" void kernel_launch(void* const* d_in, const int* in_sizes, int n_in,
                              void* d_out, int out_size, void* d_ws, size_t ws_size,
                              hipStream_t stream)
{
    const float* x    = (const float*)d_in[0];
    const int*   mask = (const int*)d_in[1];
    const float* Wq   = (const float*)d_in[2];
    const float* bq   = (const float*)d_in[3];
    const float* Wk   = (const float*)d_in[4];
    const float* bk   = (const float*)d_in[5];
    const float* Wv   = (const float*)d_in[6];
    const float* bv   = (const float*)d_in[7];
    const float* Wo   = (const float*)d_in[8];
    const float* bo   = (const float*)d_in[9];
    const float* ga   = (const float*)d_in[10];
    const float* ba   = (const float*)d_in[11];
    const float* W1   = (const float*)d_in[12];
    const float* b1   = (const float*)d_in[13];
    const float* W2   = (const float*)d_in[14];
    const float* b2   = (const float*)d_in[15];
    const float* gf   = (const float*)d_in[16];
    const float* bfb  = (const float*)d_in[17];

    size_t off = 0;
    auto alloc = [&](size_t n) { char* p = (char*)d_ws + off; off += (n + 255) & ~(size_t)255; return (void*)p; };
    bf16*   wqkvT = (bf16*)  alloc((size_t)3072 * 1024 * 2);           // 6 MB
    bf16*   WoT   = (bf16*)  alloc((size_t)1024 * 1024 * 2);           // 2 MB
    bf16*   W1T   = (bf16*)  alloc((size_t)4096 * 1024 * 2);           // 8 MB
    bf16*   W2T   = (bf16*)  alloc((size_t)1024 * 4096 * 2);           // 8 MB
    float*  bqkv  = (float*) alloc(3072 * 4);
    float2* alpha = (float2*)alloc((size_t)NB * NH * NS * 8);          // 1 MB
    int*    newpos= (int*)   alloc((size_t)NB * NS * 4);               // 32 KB
    int*    Ucnt  = (int*)   alloc(NB * 4);
    float*  cvec  = (float*) alloc((size_t)NB * NH * NDK * 4);         // 32 KB
    bf16*   xb    = (bf16*)  alloc((size_t)8192 * 1024 * 2);           // 16 MB
    // 64 MB union: Qb|Kb|Vt|ctx live until g4; hb (g5/g6) aliases the whole block
    bf16*   ub    = (bf16*)  alloc((size_t)8192 * 4096 * 2);           // 64 MB
    bf16*   Qb    = ub;
    bf16*   Kb    = ub + (size_t)8192 * 1024;
    bf16*   Vt    = ub + (size_t)2 * 8192 * 1024;
    bf16*   ctx   = ub + (size_t)3 * 8192 * 1024;
    bf16*   hb    = ub;
    // 16 MB region shared by Vb (g1->vt_trans/cvec), t1b (g4->ln1), zb (g6->ln2)
    bf16*   t1b   = (bf16*)  alloc((size_t)8192 * 1024 * 2);           // 16 MB
    bf16*   Vb    = t1b;
    bf16*   zb    = t1b;
    bf16*   yb    = (bf16*)  alloc((size_t)8192 * 1024 * 2);           // 16 MB

    cvt_x<<<8192, 256, 0, stream>>>(x, xb, 8192 * 1024 / 4);
    prep_transpose<<<3072, 256, 0, stream>>>(Wq, Wk, Wv, Wo, W1, W2, wqkvT, WoT, W1T, W2T);
    prep_bias<<<12, 256, 0, stream>>>(bq, bk, bv, bqkv);
    mask_scan<<<8, 256, 0, stream>>>(mask, newpos, Ucnt);
    g1_qkv<<<dim3(64, 24), 256, 0, stream>>>(xb, wqkvT, bqkv, newpos, Qb, Kb, Vb);
    vt_trans<<<dim3(16, 128), 256, 0, stream>>>(Vb, Vt);
    cvec_kernel<<<128, 256, 0, stream>>>(Vb, Ucnt, cvec);
    g2_stats<<<dim3(8, 128), 256, 0, stream>>>(Qb, Kb, Ucnt, alpha);
    g3_ctx<<<dim3(4, 128), 256, 0, stream>>>(Qb, Kb, Vt, alpha, Ucnt, cvec, ctx);
    g4_proj<<<dim3(64, 8), 256, 0, stream>>>(ctx, WoT, bo, xb, t1b);
    ln_kernel<<<8192, 256, 0, stream>>>(t1b, yb, nullptr, ga, ba);
    g5_ffn1<<<512, 512, 0, stream>>>(yb, W1T, b1, hb);
    g6_ffn2<<<256, 512, 0, stream>>>(hb, W2T, b2, yb, zb);
    ln_kernel<<<8192, 256, 0, stream>>>(zb, nullptr, (float*)d_out, gf, bfb);
}

// Round 8
// 472.835 us; speedup vs baseline: 1.1375x; 1.0740x over previous
//
#include <hip/hip_runtime.h>
#include <hip/hip_bf16.h>

typedef __bf16 bf16;
typedef __bf16 bf16x8 __attribute__((ext_vector_type(8)));
typedef __bf16 bf16x4 __attribute__((ext_vector_type(4)));
typedef float  f32x4  __attribute__((ext_vector_type(4)));

#define NB 8
#define NS 1024
#define ND 1024
#define NH 16
#define NDK 64
#define NDFF 4096

static __device__ __forceinline__ f32x4 mfma16(bf16x8 a, bf16x8 b, f32x4 c) {
    return __builtin_amdgcn_mfma_f32_16x16x32_bf16(a, b, c, 0, 0, 0);
}

#define GLDS(g, l) __builtin_amdgcn_global_load_lds( \
    (const __attribute__((address_space(1))) void*)(g), \
    (__attribute__((address_space(3))) void*)(l), 16, 0, 0)

// ---------------------------------------------------------------------------
// prep_all: 5 independent prep tasks merged into ONE launch (launch-overhead
// ~9-10us each; R4->R7 showed +2 tiny kernels ate ~18us). Branch is
// block-uniform; shared memory aliased through one raw buffer.
//   [0,8192)      cvt_x: fp32 x -> bf16 xb
//   [8192,11264)  weight transpose -> bf16 BT layouts (0.125 folded into Wq)
//   [11264,11276) qkv bias pack (0.125 folded into bq)
//   [11276,11284) mask scan: stable partition of key axis per batch
//   [11284,11292) zero cvec accumulator (filled by vt_trans atomics)
// ---------------------------------------------------------------------------
__global__ __launch_bounds__(256) void prep_all(
    const float* __restrict__ x, const int* __restrict__ mask,
    const float* __restrict__ Wq, const float* __restrict__ Wk, const float* __restrict__ Wv,
    const float* __restrict__ Wo, const float* __restrict__ W1, const float* __restrict__ W2,
    const float* __restrict__ bq, const float* __restrict__ bk, const float* __restrict__ bv,
    bf16* __restrict__ xb, bf16* __restrict__ wqkvT, bf16* __restrict__ WoT,
    bf16* __restrict__ W1T, bf16* __restrict__ W2T, float* __restrict__ bqkv,
    int* __restrict__ newpos, int* __restrict__ Ucnt, float* __restrict__ cvec)
{
    __shared__ __align__(16) char shraw[64 * 65 * 4];
    int bid = blockIdx.x, t = threadIdx.x;
    if (bid < 8192) {
        // ---- cvt_x: 8192 blocks x 256 thr x float4 == 8192*1024 elements ----
        int idx = bid * 256 + t;
        float4 v = ((const float4*)x)[idx];
        bf16x4 o = { (bf16)v.x, (bf16)v.y, (bf16)v.z, (bf16)v.w };
        ((bf16x4*)xb)[idx] = o;
    } else if (bid < 11264) {
        // ---- weight transpose ----
        float (*T)[65] = (float (*)[65])shraw;
        int tb = bid - 8192;
        const float* src; bf16* dst; int srcLd, dstLd, tR, tC; bool scale = false;
        if (tb < 768) {                        // Wq/Wk/Wv per-head [1024x64] -> [64x1024]
            int mat = tb >> 4, ty = tb & 15;
            int h = mat & 15, type = mat >> 4;
            const float* W = (type == 0) ? Wq : (type == 1 ? Wk : Wv);
            src = W + (size_t)h * ND * NDK;
            srcLd = NDK; tR = ty * 64; tC = 0;
            dst = wqkvT + ((size_t)type * 1024 + h * 64) * ND;
            dstLd = ND;
            scale = (type == 0);
        } else if (tb < 1024) {                // Wo
            int b2 = tb - 768; int ty = b2 >> 4, tx = b2 & 15;
            src = Wo; srcLd = ND; tR = ty * 64; tC = tx * 64; dst = WoT; dstLd = ND;
        } else if (tb < 2048) {                // W1 [1024x4096] -> W1T
            int b2 = tb - 1024; int ty = b2 >> 6, tx = b2 & 63;
            src = W1; srcLd = NDFF; tR = ty * 64; tC = tx * 64; dst = W1T; dstLd = ND;
        } else {                               // W2 [4096x1024] -> W2T
            int b2 = tb - 2048; int ty = b2 >> 4, tx = b2 & 15;
            src = W2; srcLd = ND; tR = ty * 64; tC = tx * 64; dst = W2T; dstLd = NDFF;
        }
        int c0 = t & 63, r0 = t >> 6;
        #pragma unroll
        for (int rr = 0; rr < 16; rr++) {
            int row = rr * 4 + r0;
            T[row][c0] = src[(size_t)(tR + row) * srcLd + tC + c0];
        }
        __syncthreads();
        #pragma unroll
        for (int cc = 0; cc < 16; cc++) {
            int col = cc * 4 + r0;
            float v = T[c0][col];
            if (scale) v *= 0.125f;
            dst[(size_t)(tC + col) * dstLd + tR + c0] = (bf16)v;
        }
    } else if (bid < 11276) {
        // ---- qkv bias pack ----
        int n = (bid - 11264) * 256 + t;
        if (n < 3072) {
            int type = n >> 10, hk = n & 1023;
            const float* bb = (type == 0) ? bq : (type == 1 ? bk : bv);
            float v = bb[hk];
            if (type == 0) v *= 0.125f;
            bqkv[n] = v;
        }
    } else if (bid < 11284) {
        // ---- mask scan: newpos = stable partition rank, Ucnt = #unmasked ----
        int* sums  = (int*)shraw;
        int* scans = (int*)(shraw + 1024);
        int b = bid - 11276;
        const int* mb = mask + b * NS;
        int m[4], s = 0;
        #pragma unroll
        for (int k = 0; k < 4; k++) { m[k] = (mb[t * 4 + k] != 0) ? 1 : 0; s += m[k]; }
        sums[t] = s;
        __syncthreads();
        if (t == 0) {
            int acc = 0;
            for (int i = 0; i < 256; i++) { scans[i] = acc; acc += sums[i]; }
            scans[256] = acc;
            Ucnt[b] = acc;
        }
        __syncthreads();
        int U = scans[256];
        int p = scans[t];
        #pragma unroll
        for (int k = 0; k < 4; k++) {
            int j = t * 4 + k;
            newpos[b * NS + j] = m[k] ? p : U + (j - p);
            p += m[k];
        }
    } else {
        // ---- zero cvec (8192 floats over 8 blocks) ----
        float4 z = {0.f, 0.f, 0.f, 0.f};
        ((float4*)cvec)[(bid - 11284) * 256 + t] = z;
    }
}

// ---------------------------------------------------------------------------
// Round-0 proven core: C[128x128] = A[M,K] * BT[N,K]^T. 4 waves 2x2, 256 thr.
// ---------------------------------------------------------------------------
__device__ __forceinline__ void gemm_bt_core(
    const bf16* __restrict__ A, const bf16* __restrict__ BT, int K,
    int rowBase, int colBase, f32x4 (&acc)[4][4], bf16* As, bf16* Bs)
{
    const int tid = threadIdx.x;
    const int lane = tid & 63, wid = tid >> 6;
    const int wr = (wid >> 1) * 64, wc = (wid & 1) * 64;
    const int lrow = lane & 15, lq = lane >> 4;
    const int srow = wid * 32 + (lane >> 3);
    const int gblk = (lane & 7) ^ ((lane >> 3) & 7);
    const bf16* Arow = A + (size_t)(rowBase + srow) * K + gblk * 8;
    const bf16* Brow = BT + (size_t)(colBase + srow) * K + gblk * 8;
    const int co0 = ((lq) ^ (lrow & 7)) * 8;
    const int co1 = ((4 + lq) ^ (lrow & 7)) * 8;
    f32x4 zz = {0.f, 0.f, 0.f, 0.f};
    #pragma unroll
    for (int i = 0; i < 4; i++)
        #pragma unroll
        for (int j = 0; j < 4; j++) acc[i][j] = zz;
    for (int k0 = 0; k0 < K; k0 += 64) {
        __syncthreads();
        #pragma unroll
        for (int it = 0; it < 4; it++)
            GLDS(Arow + (size_t)it * 8 * K + k0, As + (wid * 32 + it * 8) * 64);
        #pragma unroll
        for (int it = 0; it < 4; it++)
            GLDS(Brow + (size_t)it * 8 * K + k0, Bs + (wid * 32 + it * 8) * 64);
        __syncthreads();
        #pragma unroll
        for (int kh = 0; kh < 2; kh++) {
            const int co = kh ? co1 : co0;
            bf16x8 af[4], bfr[4];
            #pragma unroll
            for (int tt = 0; tt < 4; tt++) {
                af[tt]  = *(const bf16x8*)&As[(wr + tt * 16 + lrow) * 64 + co];
                bfr[tt] = *(const bf16x8*)&Bs[(wc + tt * 16 + lrow) * 64 + co];
            }
            #pragma unroll
            for (int i = 0; i < 4; i++)
                #pragma unroll
                for (int j = 0; j < 4; j++)
                    acc[i][j] = mfma16(af[i], bfr[j], acc[i][j]);
        }
    }
}

// ---------------------------------------------------------------------------
// 8-phase 256x256 core (measured best for g5).
// ---------------------------------------------------------------------------
__device__ __forceinline__ void gemm8p(
    const bf16* __restrict__ A, const bf16* __restrict__ BT, int K,
    int rowBase, int colBase, f32x4 (&acc)[8][4], bf16* As, bf16* Bs)
{
    constexpr int SETSZ = 256 * 64;
    const int tid = threadIdx.x, lane = tid & 63, wid = tid >> 6;
    const int wm = wid >> 2, wn = wid & 3;
    const int lrow = lane & 15, lq = lane >> 4;
    const int s8 = lane >> 3, gblk = (lane & 7) ^ s8;
    const int co0 = (lq ^ (lrow & 7)) * 8;
    const int co1 = ((4 + lq) ^ (lrow & 7)) * 8;
    f32x4 zz = {0.f, 0.f, 0.f, 0.f};
    #pragma unroll
    for (int i = 0; i < 8; i++)
        #pragma unroll
        for (int j = 0; j < 4; j++) acc[i][j] = zz;
    const bf16* Ag = A  + (size_t)(rowBase + wid * 8 + s8) * K + gblk * 8;
    const bf16* Bg = BT + (size_t)(colBase + wid * 8 + s8) * K + gblk * 8;

#define SG_A(kt, set, h) do { \
    GLDS(Ag + (size_t)((h) * 128) * K + (kt) * 64, \
         As + (set) * SETSZ + ((h) * 128 + wid * 8) * 64); \
    GLDS(Ag + (size_t)((h) * 128 + 64) * K + (kt) * 64, \
         As + (set) * SETSZ + ((h) * 128 + 64 + wid * 8) * 64); \
} while (0)
#define SG_B(kt, set, h) do { \
    GLDS(Bg + (size_t)((h) * 128) * K + (kt) * 64, \
         Bs + (set) * SETSZ + ((h) * 128 + wid * 8) * 64); \
    GLDS(Bg + (size_t)((h) * 128 + 64) * K + (kt) * 64, \
         Bs + (set) * SETSZ + ((h) * 128 + 64 + wid * 8) * 64); \
} while (0)
#define RD_A(dst, base, ms) do { _Pragma("unroll") for (int i_ = 0; i_ < 4; i_++) { \
    int ro_ = (wm * 128 + (ms) * 64 + i_ * 16 + lrow) * 64; \
    dst[i_][0] = *(const bf16x8*)&(base)[ro_ + co0]; \
    dst[i_][1] = *(const bf16x8*)&(base)[ro_ + co1]; } } while (0)
#define RD_B(dst, base, ns) do { _Pragma("unroll") for (int j_ = 0; j_ < 2; j_++) { \
    int ro_ = (wn * 64 + (ns) * 32 + j_ * 16 + lrow) * 64; \
    dst[j_][0] = *(const bf16x8*)&(base)[ro_ + co0]; \
    dst[j_][1] = *(const bf16x8*)&(base)[ro_ + co1]; } } while (0)
#define CL8(av, bv, ms, ns) do { \
    __builtin_amdgcn_s_setprio(1); \
    _Pragma("unroll") for (int i_ = 0; i_ < 4; i_++) \
    _Pragma("unroll") for (int j_ = 0; j_ < 2; j_++) { \
        acc[(ms) * 4 + i_][(ns) * 2 + j_] = \
            mfma16(av[i_][0], bv[j_][0], acc[(ms) * 4 + i_][(ns) * 2 + j_]); \
        acc[(ms) * 4 + i_][(ns) * 2 + j_] = \
            mfma16(av[i_][1], bv[j_][1], acc[(ms) * 4 + i_][(ns) * 2 + j_]); } \
    __builtin_amdgcn_s_setprio(0); \
} while (0)
#define BAR8 __builtin_amdgcn_s_barrier()
#define VM4 asm volatile("s_waitcnt vmcnt(4)" ::: "memory")
#define VM0 asm volatile("s_waitcnt vmcnt(0)" ::: "memory")

    const int nt = K >> 6, nIter = nt >> 1;
    SG_B(0, 0, 0); SG_B(0, 0, 1);
    SG_A(0, 0, 0); SG_A(0, 0, 1);
    SG_B(1, 1, 0); SG_B(1, 1, 1);
    VM4; BAR8;
    const bf16* A0b = As;           const bf16* B0b = Bs;
    const bf16* A1b = As + SETSZ;   const bf16* B1b = Bs + SETSZ;
    for (int J = 0; J < nIter; ++J) {
        const int v = 2 * J + 1;
        const bool pf = (J + 1 < nIter);
        bf16x8 a0[4][2], a1[4][2], b0[2][2], b1[2][2];
        // ---- K-tile u = 2J (set0) ----
        RD_A(a0, A0b, 0); RD_B(b0, B0b, 0);
        SG_A(v, 1, 0);
        BAR8; CL8(a0, b0, 0, 0); BAR8;
        RD_B(b1, B0b, 1);
        SG_A(v, 1, 1);
        BAR8; CL8(a0, b1, 0, 1); BAR8;
        RD_A(a1, A0b, 1);
        if (pf) SG_B(v + 1, 0, 0);
        BAR8; CL8(a1, b1, 1, 1); BAR8;
        if (pf) SG_B(v + 1, 0, 1);
        BAR8; CL8(a1, b0, 1, 0);
        if (pf) { VM4; } else { VM0; }
        BAR8;
        // ---- K-tile v = 2J+1 (set1) ----
        RD_A(a0, A1b, 0); RD_B(b0, B1b, 0);
        if (pf) SG_A(v + 1, 0, 0);
        BAR8; CL8(a0, b0, 0, 0); BAR8;
        RD_B(b1, B1b, 1);
        if (pf) SG_A(v + 1, 0, 1);
        BAR8; CL8(a0, b1, 0, 1); BAR8;
        RD_A(a1, A1b, 1);
        if (pf) SG_B(v + 2, 1, 0);
        BAR8; CL8(a1, b1, 1, 1); BAR8;
        if (pf) SG_B(v + 2, 1, 1);
        BAR8; CL8(a1, b0, 1, 0);
        if (pf) { VM4; } else { VM0; }
        BAR8;
    }
#undef SG_A
#undef SG_B
#undef RD_A
#undef RD_B
#undef CL8
#undef BAR8
#undef VM4
#undef VM0
}

// ---------------------------------------------------------------------------
// Core B (measured 857 TF on g6): 128x256, BK=64, 8 waves, 2 phases x 16
// MFMA, TRIPLE-buf LDS (144 KiB): stage tile t+2 during tile t, vmcnt(6).
// ---------------------------------------------------------------------------
__device__ __forceinline__ void gemmB_core(
    const bf16* __restrict__ A, const bf16* __restrict__ BT, int K,
    int rowBase, int colBase, f32x4 (&acc)[4][4], bf16* As, bf16* Bs)
{
    constexpr int ABUF = 128 * 64, BBUF = 256 * 64;
    const int tid = threadIdx.x, lane = tid & 63, wid = tid >> 6;
    const int wm = wid >> 2, wn = wid & 3;
    const int lrow = lane & 15, lq = lane >> 4;
    const int srow = lane >> 3, gblk = (lane & 7) ^ srow;
    const int co0 = (lq ^ (lrow & 7)) * 8;
    const int co1 = ((4 + lq) ^ (lrow & 7)) * 8;
    f32x4 zz = {0.f, 0.f, 0.f, 0.f};
    #pragma unroll
    for (int i = 0; i < 4; i++)
        #pragma unroll
        for (int j = 0; j < 4; j++) acc[i][j] = zz;
    const bf16* Ag = A  + (size_t)(rowBase + wid * 8 + srow) * K + gblk * 8;
    const bf16* Bg = BT + (size_t)(colBase + wid * 8 + srow) * K + gblk * 8;

#define SGA2(kt, bi, rr) GLDS(Ag + (size_t)(kt) * 64 + (size_t)(rr) * 64 * K, \
                              As + (bi) * ABUF + ((rr) * 64 + wid * 8) * 64)
#define SGB2(kt, bi, rr) GLDS(Bg + (size_t)(kt) * 64 + (size_t)(rr) * 64 * K, \
                              Bs + (bi) * BBUF + ((rr) * 64 + wid * 8) * 64)
#define RDA2() do { _Pragma("unroll") for (int i_ = 0; i_ < 4; i_++) { \
    int ro_ = (wm * 64 + i_ * 16 + lrow) * 64; \
    af[i_][0] = *(const bf16x8*)&Ab[ro_ + co0]; \
    af[i_][1] = *(const bf16x8*)&Ab[ro_ + co1]; } } while (0)
#define RDB2(dst, NS_) do { _Pragma("unroll") for (int j_ = 0; j_ < 2; j_++) { \
    int ro_ = (wn * 64 + (NS_) * 32 + j_ * 16 + lrow) * 64; \
    dst[j_][0] = *(const bf16x8*)&Bb[ro_ + co0]; \
    dst[j_][1] = *(const bf16x8*)&Bb[ro_ + co1]; } } while (0)
#define CLUSTER_B(bfx, JO) do { \
    __builtin_amdgcn_s_barrier(); \
    asm volatile("s_waitcnt lgkmcnt(0)" ::: "memory"); \
    __builtin_amdgcn_sched_barrier(0); \
    __builtin_amdgcn_s_setprio(1); \
    _Pragma("unroll") \
    for (int i_ = 0; i_ < 4; i_++) \
        _Pragma("unroll") \
        for (int j_ = 0; j_ < 2; j_++) { \
            acc[i_][(JO) + j_] = mfma16(af[i_][0], bfx[j_][0], acc[i_][(JO) + j_]); \
            acc[i_][(JO) + j_] = mfma16(af[i_][1], bfx[j_][1], acc[i_][(JO) + j_]); \
        } \
    __builtin_amdgcn_s_setprio(0); \
} while (0)

    const int nt = K >> 6;
    SGA2(0, 0, 0); SGA2(0, 0, 1);
    SGB2(0, 0, 0); SGB2(0, 0, 1); SGB2(0, 0, 2); SGB2(0, 0, 3);
    SGA2(1, 1, 0); SGA2(1, 1, 1);
    SGB2(1, 1, 0); SGB2(1, 1, 1); SGB2(1, 1, 2); SGB2(1, 1, 3);
    asm volatile("s_waitcnt vmcnt(6)" ::: "memory");
    __builtin_amdgcn_s_barrier();

    int ci = 0, si = 2;
    for (int t = 0; t < nt; ++t) {
        const bf16* Ab = As + ci * ABUF;
        const bf16* Bb = Bs + ci * BBUF;
        const bool pf = (t + 2 < nt);
        bf16x8 af[4][2], bf0[2][2], bf1[2][2];
        RDA2(); RDB2(bf0, 0);
        if (pf) { SGA2(t + 2, si, 0); SGA2(t + 2, si, 1); SGB2(t + 2, si, 0); SGB2(t + 2, si, 1); }
        CLUSTER_B(bf0, 0);
        __builtin_amdgcn_s_barrier();
        RDB2(bf1, 1);
        if (pf) { SGB2(t + 2, si, 2); SGB2(t + 2, si, 3); }
        CLUSTER_B(bf1, 2);
        if (pf)                asm volatile("s_waitcnt vmcnt(6)" ::: "memory");
        else if (t + 1 < nt)   asm volatile("s_waitcnt vmcnt(0)" ::: "memory");
        __builtin_amdgcn_s_barrier();
        ci = (ci == 2) ? 0 : ci + 1;
        si = (si == 2) ? 0 : si + 1;
    }
#undef SGA2
#undef SGB2
#undef RDA2
#undef RDB2
#undef CLUSTER_B
}

// G1: xb @ [Wq|Wk|Wv] + bias; Q row-major, K/V rows through newpos (compacted).
// Core B (128x256), grid 768 (64 bm x 12 bn), XCD-swizzled (768 % 8 == 0).
__global__ __launch_bounds__(512, 2) void g1_qkv(
    const bf16* __restrict__ x, const bf16* __restrict__ wqkvT, const float* __restrict__ bqkv,
    const int* __restrict__ newpos,
    bf16* __restrict__ Q, bf16* __restrict__ Kb, bf16* __restrict__ Vb)
{
    __shared__ bf16 As[3 * 128 * 64], Bs[3 * 256 * 64];   // 144 KiB
    f32x4 acc[4][4];
    int g = blockIdx.x;
    int sw = (g & 7) * 96 + (g >> 3);
    int bm = sw / 12, bn = sw % 12;
    int rowBase = bm * 128, colBase = bn * 256;
    gemmB_core(x, wqkvT, ND, rowBase, colBase, acc, As, Bs);
    const int tid = threadIdx.x, lane = tid & 63, wid = tid >> 6;
    const int wm = wid >> 2, wn = wid & 3, lrow = lane & 15, lq = lane >> 4;
    const int type = colBase >> 10;   // 256 | 1024, so each tile is within one of Q/K/V
    int spv[4][4];
    if (type != 0) {
        #pragma unroll
        for (int i = 0; i < 4; i++)
            #pragma unroll
            for (int r = 0; r < 4; r++) {
                int grow = rowBase + wm * 64 + i * 16 + lq * 4 + r;
                spv[i][r] = newpos[grow];   // == newpos[b*NS + s]
            }
    }
    #pragma unroll
    for (int j = 0; j < 4; j++) {
        int gcol = colBase + wn * 64 + j * 16 + lrow;
        float bias = bqkv[gcol];
        int h = (gcol >> 6) & 15, kk = gcol & 63;
        bf16* dst = (type == 0) ? Q : (type == 1 ? Kb : Vb);
        #pragma unroll
        for (int i = 0; i < 4; i++) {
            #pragma unroll
            for (int r = 0; r < 4; r++) {
                int grow = rowBase + wm * 64 + i * 16 + lq * 4 + r;
                int b = grow >> 10;
                int s = (type == 0) ? (grow & 1023) : spv[i][r];
                dst[((size_t)(b * NH + h) * NS + s) * NDK + kk] = (bf16)(acc[i][j][r] + bias);
            }
        }
    }
}

// Vb [bh][s][kk] -> Vt [bh][kk][s]  (LDS-tiled transpose; compacted order).
// ALSO accumulates the masked-tail column sums into cvec (raw sums; g3 scales
// by 1/1024) -- replaces the separate cvec kernel (launch-count reduction).
__global__ __launch_bounds__(256) void vt_trans(
    const bf16* __restrict__ Vb, const int* __restrict__ Ucnt,
    bf16* __restrict__ Vt, float* __restrict__ cvec)
{
    __shared__ bf16 T[64 * 72];
    __shared__ float red[4][64];
    int bh = blockIdx.y, s0 = blockIdx.x * 64;
    const bf16* src = Vb + ((size_t)bh * NS + s0) * NDK;
    int tid = threadIdx.x;
    #pragma unroll
    for (int it = 0; it < 2; it++) {
        int g = tid + it * 256;
        int row = g >> 3, c = (g & 7) * 8;
        *(bf16x8*)&T[row * 72 + c] = *(const bf16x8*)&src[row * NDK + c];
    }
    __syncthreads();
    #pragma unroll
    for (int it = 0; it < 2; it++) {
        int g = tid + it * 256;
        int kk = g >> 3, sc = (g & 7) * 8;
        bf16x8 v;
        #pragma unroll
        for (int t = 0; t < 8; t++) v[t] = T[(sc + t) * 72 + kk];
        *(bf16x8*)&Vt[((size_t)bh * NDK + kk) * NS + s0 + sc] = v;
    }
    // masked-tail contribution: rows with compacted s >= U_b
    int U = Ucnt[bh >> 4];
    int lo = U - s0;
    if (lo < 0) lo = 0;
    if (lo < 64) {                         // block-uniform branch
        int kk = tid & 63, ss = tid >> 6;
        float a = 0.f;
        for (int r = lo + ss; r < 64; r += 4) a += (float)T[r * 72 + kk];
        red[ss][kk] = a;
        __syncthreads();
        if (ss == 0)
            atomicAdd(&cvec[bh * 64 + kk], red[0][kk] + red[1][kk] + red[2][kk] + red[3][kk]);
    }
}

// G2: column-sum coefficients over COMPACTED keys. Tiles with jBase >= U_b
// just zero their alpha entries. Masked keys handled by cvec in g3.
__global__ __launch_bounds__(256) void g2_stats(
    const bf16* __restrict__ Q, const bf16* __restrict__ Kb,
    const int* __restrict__ Ucnt, float2* __restrict__ alpha)
{
    __shared__ bf16 Qs[128 * 64];
    int bh = blockIdx.y, b = bh >> 4;
    int jBase = blockIdx.x * 128;
    int U = Ucnt[b];
    const int tid = threadIdx.x;
    if (jBase >= U) {                      // whole tile masked/padded
        if (tid < 128) {
            float2 z; z.x = 0.f; z.y = 0.f;
            alpha[(size_t)bh * NS + jBase + tid] = z;
        }
        return;
    }
    const bf16* Kp = Kb + (size_t)bh * NS * NDK;
    const bf16* Qp = Q + (size_t)bh * NS * NDK;
    const int lane = tid & 63, wid = tid >> 6;
    const int lrow = lane & 15, lq = lane >> 4;
    bf16x8 kf[2][2];
    #pragma unroll
    for (int jt = 0; jt < 2; jt++)
        #pragma unroll
        for (int kh = 0; kh < 2; kh++)
            kf[jt][kh] = *(const bf16x8*)&Kp[(size_t)(jBase + wid * 32 + jt * 16 + lrow) * NDK + kh * 32 + lq * 8];
    const int srow = lane >> 3;
    const int gblk = (lane & 7) ^ srow;
    float Lacc[2][4];
    #pragma unroll
    for (int jt = 0; jt < 2; jt++)
        #pragma unroll
        for (int r = 0; r < 4; r++) Lacc[jt][r] = 0.f;
    f32x4 zz = {0.f, 0.f, 0.f, 0.f};
    for (int i0 = 0; i0 < NS; i0 += 128) {
        __syncthreads();
        #pragma unroll
        for (int it = 0; it < 4; it++)
            GLDS(Qp + (size_t)(i0 + wid * 32 + it * 8 + srow) * NDK + gblk * 8,
                 Qs + (wid * 32 + it * 8) * 64);
        __syncthreads();
        #pragma unroll
        for (int it = 0; it < 8; it++) {
            bf16x8 qb[2];
            #pragma unroll
            for (int kh = 0; kh < 2; kh++)
                qb[kh] = *(const bf16x8*)&Qs[(it * 16 + lrow) * 64 + ((kh * 4 + lq) ^ (lrow & 7)) * 8];
            #pragma unroll
            for (int jt = 0; jt < 2; jt++) {
                f32x4 s = mfma16(kf[jt][0], qb[0], zz);
                s = mfma16(kf[jt][1], qb[1], s);
                #pragma unroll
                for (int r = 0; r < 4; r++) Lacc[jt][r] += __expf(s[r]);
            }
        }
    }
    #pragma unroll
    for (int jt = 0; jt < 2; jt++) {
        #pragma unroll
        for (int r = 0; r < 4; r++) {
            float v = Lacc[jt][r];
            v += __shfl_xor(v, 1); v += __shfl_xor(v, 2);
            v += __shfl_xor(v, 4); v += __shfl_xor(v, 8);
            if (lrow == 0) {
                int j = jBase + wid * 32 + jt * 16 + lq * 4 + r;
                float2 ac;
                ac.x = (j < U) ? 1.f / v : 0.f;
                ac.y = 0.f;
                alpha[(size_t)bh * NS + j] = ac;
            }
        }
    }
}

// G3: ctx[i][kk] = sum_{compacted j < Ur} a_j*exp(s_ij) * v[j][kk] + cvec/1024
__global__ __launch_bounds__(256) void g3_ctx(
    const bf16* __restrict__ Q, const bf16* __restrict__ Kb, const bf16* __restrict__ Vt,
    const float2* __restrict__ alpha, const int* __restrict__ Ucnt,
    const float* __restrict__ cvec, bf16* __restrict__ ctx)
{
    __shared__ bf16 Ks[64 * 64];       // 8 KB
    __shared__ bf16 Vs[64 * 64];       // 8 KB
    __shared__ bf16 Ps[4 * 64 * 64];   // 32 KB, per-wave 8KB, XOR-swizzled
    int bh = blockIdx.y, iBase = blockIdx.x * 256;
    int b = bh >> 4, h = bh & 15;
    int U = Ucnt[b];
    int Ur = (U + 63) & ~63;           // j-tiles only over compacted unmasked keys
    const bf16* Qp = Q + (size_t)bh * NS * NDK;
    const bf16* Kp = Kb + (size_t)bh * NS * NDK;
    const bf16* Vp = Vt + (size_t)bh * NDK * NS;
    const float2* al = alpha + (size_t)bh * NS;
    const int tid = threadIdx.x, lane = tid & 63, wid = tid >> 6;
    const int lrow = lane & 15, lq = lane >> 4;
    const int iw = iBase + wid * 64;
    bf16x8 qf[4][2];
    #pragma unroll
    for (int it = 0; it < 4; it++)
        #pragma unroll
        for (int kh = 0; kh < 2; kh++)
            qf[it][kh] = *(const bf16x8*)&Qp[(size_t)(iw + it * 16 + lrow) * NDK + kh * 32 + lq * 8];
    const int srow = lane >> 3;
    const int gblk = (lane & 7) ^ srow;
    f32x4 cacc[4][4];
    f32x4 zz = {0.f, 0.f, 0.f, 0.f};
    #pragma unroll
    for (int it = 0; it < 4; it++)
        #pragma unroll
        for (int kt = 0; kt < 4; kt++) cacc[it][kt] = zz;
    bf16* Pw = Ps + wid * 64 * 64;
    for (int j0 = 0; j0 < Ur; j0 += 64) {
        __syncthreads();
        #pragma unroll
        for (int it = 0; it < 2; it++)
            GLDS(Kp + (size_t)(j0 + wid * 16 + it * 8 + srow) * NDK + gblk * 8,
                 Ks + (wid * 16 + it * 8) * 64);
        #pragma unroll
        for (int it = 0; it < 2; it++)
            GLDS(Vp + (size_t)(wid * 16 + it * 8 + srow) * NS + j0 + gblk * 8,
                 Vs + (wid * 16 + it * 8) * 64);
        __syncthreads();
        bf16x8 kb[4][2];
        #pragma unroll
        for (int jt = 0; jt < 4; jt++)
            #pragma unroll
            for (int kh = 0; kh < 2; kh++)
                kb[jt][kh] = *(const bf16x8*)&Ks[(jt * 16 + lrow) * 64 + ((kh * 4 + lq) ^ (lrow & 7)) * 8];
        #pragma unroll
        for (int jt = 0; jt < 4; jt++) {
            float2 acj[4];
            #pragma unroll
            for (int r = 0; r < 4; r++) acj[r] = al[j0 + jt * 16 + lq * 4 + r];
            #pragma unroll
            for (int it = 0; it < 4; it++) {
                f32x4 s = mfma16(kb[jt][0], qf[it][0], zz);
                s = mfma16(kb[jt][1], qf[it][1], s);
                bf16x4 pv;
                #pragma unroll
                for (int r = 0; r < 4; r++)
                    pv[r] = (bf16)(acj[r].x * __expf(s[r]) + acj[r].y);
                int i = it * 16 + lrow;
                int jb = jt * 2 + (lq >> 1);
                *(bf16x4*)&Pw[i * 64 + ((jb ^ (i & 7)) * 8) + (lq & 1) * 4] = pv;
            }
        }
        bf16x8 vb[4][2];
        #pragma unroll
        for (int kt = 0; kt < 4; kt++)
            #pragma unroll
            for (int kh = 0; kh < 2; kh++)
                vb[kt][kh] = *(const bf16x8*)&Vs[(kt * 16 + lrow) * 64 + ((kh * 4 + lq) ^ (lrow & 7)) * 8];
        #pragma unroll
        for (int it = 0; it < 4; it++) {
            bf16x8 pa[2];
            #pragma unroll
            for (int kh = 0; kh < 2; kh++)
                pa[kh] = *(const bf16x8*)&Pw[(it * 16 + lrow) * 64 + ((kh * 4 + lq) ^ (lrow & 7)) * 8];
            #pragma unroll
            for (int kt = 0; kt < 4; kt++) {
                cacc[it][kt] = mfma16(pa[0], vb[kt][0], cacc[it][kt]);
                cacc[it][kt] = mfma16(pa[1], vb[kt][1], cacc[it][kt]);
            }
        }
    }
    #pragma unroll
    for (int kt = 0; kt < 4; kt++) {
        int col = h * NDK + kt * 16 + lrow;
        float cv = cvec[bh * 64 + kt * 16 + lrow] * (1.f / 1024.f);
        #pragma unroll
        for (int it = 0; it < 4; it++) {
            #pragma unroll
            for (int r = 0; r < 4; r++) {
                int i = iw + it * 16 + lq * 4 + r;
                ctx[(size_t)(b * NS + i) * ND + col] = (bf16)(cacc[it][kt][r] + cv);
            }
        }
    }
}

// G4: t1b = bf16(ctx @ Wo + bo + xb)   (128^2 core)
__global__ __launch_bounds__(256) void g4_proj(
    const bf16* __restrict__ ctx, const bf16* __restrict__ WoT, const float* __restrict__ bo,
    const bf16* __restrict__ xb, bf16* __restrict__ t1b)
{
    __shared__ bf16 As[128 * 64], Bs[128 * 64];
    f32x4 acc[4][4];
    int rowBase = blockIdx.x * 128, colBase = blockIdx.y * 128;
    gemm_bt_core(ctx, WoT, ND, rowBase, colBase, acc, As, Bs);
    const int tid = threadIdx.x, lane = tid & 63, wid = tid >> 6;
    const int wr = (wid >> 1) * 64, wc = (wid & 1) * 64, lrow = lane & 15, lq = lane >> 4;
    #pragma unroll
    for (int j = 0; j < 4; j++) {
        int gcol = colBase + wc + j * 16 + lrow;
        float bias = bo[gcol];
        #pragma unroll
        for (int i = 0; i < 4; i++) {
            #pragma unroll
            for (int r = 0; r < 4; r++) {
                int grow = rowBase + wr + i * 16 + lq * 4 + r;
                float v = acc[i][j][r] + bias + (float)xb[(size_t)grow * ND + gcol];
                t1b[(size_t)grow * ND + gcol] = (bf16)v;
            }
        }
    }
}

// G5: hb = relu(yb @ W1 + b1)   8-phase core, grid 512 (32x16)
__global__ __launch_bounds__(512, 2) void g5_ffn1(
    const bf16* __restrict__ y, const bf16* __restrict__ W1T, const float* __restrict__ b1,
    bf16* __restrict__ hb)
{
    __shared__ bf16 As[2 * 256 * 64], Bs[2 * 256 * 64];   // 128 KiB
    f32x4 acc[8][4];
    int g = blockIdx.x;
    int sw = (g & 7) * 64 + (g >> 3);
    int bm = sw >> 4, bn = sw & 15;
    int rowBase = bm * 256, colBase = bn * 256;
    gemm8p(y, W1T, ND, rowBase, colBase, acc, As, Bs);
    const int tid = threadIdx.x, lane = tid & 63, wid = tid >> 6;
    const int wm = wid >> 2, wn = wid & 3, lrow = lane & 15, lq = lane >> 4;
    #pragma unroll
    for (int j = 0; j < 4; j++) {
        int gcol = colBase + wn * 64 + j * 16 + lrow;
        float bias = b1[gcol];
        #pragma unroll
        for (int i = 0; i < 8; i++) {
            #pragma unroll
            for (int r = 0; r < 4; r++) {
                int grow = rowBase + wm * 128 + i * 16 + lq * 4 + r;
                float v = fmaxf(acc[i][j][r] + bias, 0.f);
                hb[(size_t)grow * NDFF + gcol] = (bf16)v;
            }
        }
    }
}

// G6: zb = bf16(hb @ W2 + b2 + yb)   core B, grid 256, K=4096
__global__ __launch_bounds__(512, 2) void g6_ffn2(
    const bf16* __restrict__ hb, const bf16* __restrict__ W2T, const float* __restrict__ b2,
    const bf16* __restrict__ yb, bf16* __restrict__ zb)
{
    __shared__ bf16 As[3 * 128 * 64], Bs[3 * 256 * 64];   // 144 KiB
    f32x4 acc[4][4];
    int g = blockIdx.x;
    int sw = (g & 7) * 32 + (g >> 3);
    int bm = sw >> 2, bn = sw & 3;
    int rowBase = bm * 128, colBase = bn * 256;
    gemmB_core(hb, W2T, NDFF, rowBase, colBase, acc, As, Bs);
    const int tid = threadIdx.x, lane = tid & 63, wid = tid >> 6;
    const int wm = wid >> 2, wn = wid & 3, lrow = lane & 15, lq = lane >> 4;
    #pragma unroll
    for (int j = 0; j < 4; j++) {
        int gcol = colBase + wn * 64 + j * 16 + lrow;
        float bias = b2[gcol];
        #pragma unroll
        for (int i = 0; i < 4; i++) {
            #pragma unroll
            for (int r = 0; r < 4; r++) {
                int grow = rowBase + wm * 64 + i * 16 + lq * 4 + r;
                float v = acc[i][j][r] + bias + (float)yb[(size_t)grow * ND + gcol];
                zb[(size_t)grow * ND + gcol] = (bf16)v;
            }
        }
    }
}

// Row LayerNorm over D=1024, bf16 in; writes bf16 (outb) and/or fp32 (outf)
__global__ __launch_bounds__(256) void ln_kernel(
    const bf16* __restrict__ in, bf16* __restrict__ outb, float* __restrict__ outf,
    const float* __restrict__ g, const float* __restrict__ bb)
{
    int row = blockIdx.x, tid = threadIdx.x;
    const bf16* p = in + (size_t)row * ND;
    bf16x4 v4 = *(const bf16x4*)&p[tid * 4];
    float vv[4] = {(float)v4[0], (float)v4[1], (float)v4[2], (float)v4[3]};
    float s = vv[0] + vv[1] + vv[2] + vv[3];
    float q = vv[0]*vv[0] + vv[1]*vv[1] + vv[2]*vv[2] + vv[3]*vv[3];
    #pragma unroll
    for (int m = 1; m < 64; m <<= 1) { s += __shfl_xor(s, m); q += __shfl_xor(q, m); }
    __shared__ float rs[4], rq[4];
    int wid = tid >> 6, lane = tid & 63;
    if (lane == 0) { rs[wid] = s; rq[wid] = q; }
    __syncthreads();
    s = rs[0] + rs[1] + rs[2] + rs[3];
    q = rq[0] + rq[1] + rq[2] + rq[3];
    float mean = s * (1.f / 1024.f);
    float var = q * (1.f / 1024.f) - mean * mean;
    float rstd = 1.f / sqrtf(var + 1e-5f);
    float4 of;
    bf16x4 ob;
    #pragma unroll
    for (int k = 0; k < 4; k++) {
        int col = tid * 4 + k;
        float yv = (vv[k] - mean) * rstd * g[col] + bb[col];
        ((float*)&of)[k] = yv;
        ob[k] = (bf16)yv;
    }
    if (outb) *(bf16x4*)&outb[(size_t)row * ND + tid * 4] = ob;
    if (outf) ((float4*)(outf + (size_t)row * ND))[tid] = of;
}

// ---------------------------------------------------------------------------
extern "C" void kernel_launch(void* const* d_in, const int* in_sizes, int n_in,
                              void* d_out, int out_size, void* d_ws, size_t ws_size,
                              hipStream_t stream)
{
    const float* x    = (const float*)d_in[0];
    const int*   mask = (const int*)d_in[1];
    const float* Wq   = (const float*)d_in[2];
    const float* bq   = (const float*)d_in[3];
    const float* Wk   = (const float*)d_in[4];
    const float* bk   = (const float*)d_in[5];
    const float* Wv   = (const float*)d_in[6];
    const float* bv   = (const float*)d_in[7];
    const float* Wo   = (const float*)d_in[8];
    const float* bo   = (const float*)d_in[9];
    const float* ga   = (const float*)d_in[10];
    const float* ba   = (const float*)d_in[11];
    const float* W1   = (const float*)d_in[12];
    const float* b1   = (const float*)d_in[13];
    const float* W2   = (const float*)d_in[14];
    const float* b2   = (const float*)d_in[15];
    const float* gf   = (const float*)d_in[16];
    const float* bfb  = (const float*)d_in[17];

    size_t off = 0;
    auto alloc = [&](size_t n) { char* p = (char*)d_ws + off; off += (n + 255) & ~(size_t)255; return (void*)p; };
    bf16*   wqkvT = (bf16*)  alloc((size_t)3072 * 1024 * 2);           // 6 MB
    bf16*   WoT   = (bf16*)  alloc((size_t)1024 * 1024 * 2);           // 2 MB
    bf16*   W1T   = (bf16*)  alloc((size_t)4096 * 1024 * 2);           // 8 MB
    bf16*   W2T   = (bf16*)  alloc((size_t)1024 * 4096 * 2);           // 8 MB
    float*  bqkv  = (float*) alloc(3072 * 4);
    float2* alpha = (float2*)alloc((size_t)NB * NH * NS * 8);          // 1 MB
    int*    newpos= (int*)   alloc((size_t)NB * NS * 4);               // 32 KB
    int*    Ucnt  = (int*)   alloc(NB * 4);
    float*  cvec  = (float*) alloc((size_t)NB * NH * NDK * 4);         // 32 KB
    bf16*   xb    = (bf16*)  alloc((size_t)8192 * 1024 * 2);           // 16 MB
    // 64 MB union: Qb|Kb|Vt|ctx live until g4; hb (g5/g6) aliases the whole block
    bf16*   ub    = (bf16*)  alloc((size_t)8192 * 4096 * 2);           // 64 MB
    bf16*   Qb    = ub;
    bf16*   Kb    = ub + (size_t)8192 * 1024;
    bf16*   Vt    = ub + (size_t)2 * 8192 * 1024;
    bf16*   ctx   = ub + (size_t)3 * 8192 * 1024;
    bf16*   hb    = ub;
    // 16 MB region shared by Vb (g1->vt_trans), t1b (g4->ln1), zb (g6->ln2)
    bf16*   t1b   = (bf16*)  alloc((size_t)8192 * 1024 * 2);           // 16 MB
    bf16*   Vb    = t1b;
    bf16*   zb    = t1b;
    bf16*   yb    = (bf16*)  alloc((size_t)8192 * 1024 * 2);           // 16 MB

    // 10 launches (was 14): prep fused; cvec folded into vt_trans.
    prep_all<<<11292, 256, 0, stream>>>(x, mask, Wq, Wk, Wv, Wo, W1, W2, bq, bk, bv,
                                        xb, wqkvT, WoT, W1T, W2T, bqkv, newpos, Ucnt, cvec);
    g1_qkv<<<768, 512, 0, stream>>>(xb, wqkvT, bqkv, newpos, Qb, Kb, Vb);
    vt_trans<<<dim3(16, 128), 256, 0, stream>>>(Vb, Ucnt, Vt, cvec);
    g2_stats<<<dim3(8, 128), 256, 0, stream>>>(Qb, Kb, Ucnt, alpha);
    g3_ctx<<<dim3(4, 128), 256, 0, stream>>>(Qb, Kb, Vt, alpha, Ucnt, cvec, ctx);
    g4_proj<<<dim3(64, 8), 256, 0, stream>>>(ctx, WoT, bo, xb, t1b);
    ln_kernel<<<8192, 256, 0, stream>>>(t1b, yb, nullptr, ga, ba);
    g5_ffn1<<<512, 512, 0, stream>>>(yb, W1T, b1, hb);
    g6_ffn2<<<256, 512, 0, stream>>>(hb, W2T, b2, yb, zb);
    ln_kernel<<<8192, 256, 0, stream>>>(zb, nullptr, (float*)d_out, gf, bfb);
}